// Round 1
// baseline (5117.594 us; speedup 1.0000x reference)
//
#include <hip/hip_runtime.h>
#include <math.h>

#define TT   24
#define NN   10000
#define DIN  128
#define H1C  256
#define H2C  128
#define OUTD 100
#define FLATSZ (NN*H2C)

__device__ __forceinline__ float sigmoidf_(float x){ return 1.0f/(1.0f+expf(-x)); }

// ---------------- small utility kernels ----------------

__global__ __launch_bounds__(256) void zero_f32_kernel(float* __restrict__ p, int n){
  int i = blockIdx.x*256 + threadIdx.x;
  if (i < n) p[i] = 0.0f;
}

__global__ __launch_bounds__(256) void init_kernel(int* __restrict__ cnt, int* __restrict__ cursor,
                                                   float* __restrict__ logits, int n){
  int i = blockIdx.x*256 + threadIdx.x;
  if (i < n){ cnt[i] = 0; cursor[i] = 0; }
  if (i < OUTD) logits[i] = 0.0f;
}

__global__ __launch_bounds__(256) void count_kernel(const int* __restrict__ ei, int* __restrict__ cnt, int E){
  int e = blockIdx.x*256 + threadIdx.x;
  if (e < E) atomicAdd(&cnt[ei[E + e]], 1);
}

__global__ __launch_bounds__(256) void dis_kernel(const int* __restrict__ cnt, float* __restrict__ dis, int n){
  int i = blockIdx.x*256 + threadIdx.x;
  if (i < n) dis[i] = rsqrtf((float)(cnt[i] + 1));   // +1 self-loop; deg>=1 always
}

// single-block exclusive scan of cnt[0..n) -> off[0..n], off[n]=total
__global__ __launch_bounds__(256) void scan_kernel(const int* __restrict__ cnt, int* __restrict__ off, int n){
  __shared__ int sums[256];
  const int tid = threadIdx.x;
  const int CH  = 40;                  // 256*40 = 10240 >= NN
  const int base = tid*CH;
  int s = 0;
  for (int i = 0; i < CH; ++i){ int idx = base + i; if (idx < n) s += cnt[idx]; }
  sums[tid] = s; __syncthreads();
  for (int d = 1; d < 256; d <<= 1){
    int v = (tid >= d) ? sums[tid - d] : 0;
    __syncthreads();
    sums[tid] += v;
    __syncthreads();
  }
  int run = (tid == 0) ? 0 : sums[tid - 1];
  for (int i = 0; i < CH; ++i){
    int idx = base + i;
    if (idx < n){ off[idx] = run; run += cnt[idx]; }
  }
  if (tid == 0) off[n] = sums[255];
}

__global__ __launch_bounds__(256) void scatter_kernel(const int* __restrict__ ei, const float* __restrict__ dis,
                                                      const int* __restrict__ off, int* __restrict__ cursor,
                                                      int* __restrict__ perm, float* __restrict__ ew, int E){
  int e = blockIdx.x*256 + threadIdx.x;
  if (e < E){
    int r = ei[e];
    int c = ei[E + e];
    int pos = off[c] + atomicAdd(&cursor[c], 1);
    perm[pos] = r;
    ew[pos]   = dis[r]*dis[c];
  }
}

// ---------------- GEMM: C[m][n] = sum_k A[m][k]*W[n][k] + bias[n] ----------------
// BM=64, BN=64, BK=32, 256 threads, 4x4 microtile. Ncols must be a multiple of 64.
__global__ __launch_bounds__(256) void gemm_bias_kernel(
    const float* __restrict__ A, const float* __restrict__ W,
    const float* __restrict__ bias, float* __restrict__ C,
    int M, int Ncols, int K)
{
  __shared__ float As[32][68];
  __shared__ float Bs[32][68];
  const int tid = threadIdx.x;
  const int tx = tid & 15, ty = tid >> 4;
  const int m0 = blockIdx.x * 64;
  const int n0 = blockIdx.y * 64;
  const int lrow = tid >> 2;
  const int lk   = (tid & 3) * 8;
  float acc[4][4] = {};

  for (int k0 = 0; k0 < K; k0 += 32){
    {
      const int m = m0 + lrow;
      float4 v0 = make_float4(0.f,0.f,0.f,0.f), v1 = v0;
      if (m < M){
        const float* src = &A[(size_t)m*K + k0 + lk];
        v0 = *(const float4*)src;
        v1 = *(const float4*)(src + 4);
      }
      As[lk+0][lrow]=v0.x; As[lk+1][lrow]=v0.y; As[lk+2][lrow]=v0.z; As[lk+3][lrow]=v0.w;
      As[lk+4][lrow]=v1.x; As[lk+5][lrow]=v1.y; As[lk+6][lrow]=v1.z; As[lk+7][lrow]=v1.w;
      const float* wsrc = &W[(size_t)(n0 + lrow)*K + k0 + lk];
      float4 w0 = *(const float4*)wsrc, w1 = *(const float4*)(wsrc + 4);
      Bs[lk+0][lrow]=w0.x; Bs[lk+1][lrow]=w0.y; Bs[lk+2][lrow]=w0.z; Bs[lk+3][lrow]=w0.w;
      Bs[lk+4][lrow]=w1.x; Bs[lk+5][lrow]=w1.y; Bs[lk+6][lrow]=w1.z; Bs[lk+7][lrow]=w1.w;
    }
    __syncthreads();
    #pragma unroll
    for (int k = 0; k < 32; ++k){
      const float4 a = *(const float4*)&As[k][ty*4];
      const float4 b = *(const float4*)&Bs[k][tx*4];
      const float av[4] = {a.x,a.y,a.z,a.w};
      const float bv[4] = {b.x,b.y,b.z,b.w};
      #pragma unroll
      for (int i = 0; i < 4; ++i)
        #pragma unroll
        for (int j = 0; j < 4; ++j)
          acc[i][j] = fmaf(av[i], bv[j], acc[i][j]);
    }
    __syncthreads();
  }

  const float4 bb = *(const float4*)&bias[n0 + tx*4];
  const float bv[4] = {bb.x,bb.y,bb.z,bb.w};
  #pragma unroll
  for (int i = 0; i < 4; ++i){
    const int m = m0 + ty*4 + i;
    if (m < M){
      float4 o;
      o.x = acc[i][0] + bv[0];
      o.y = acc[i][1] + bv[1];
      o.z = acc[i][2] + bv[2];
      o.w = acc[i][3] + bv[3];
      *(float4*)&C[(size_t)m*Ncols + n0 + tx*4] = o;
    }
  }
}

// ---------------- fused GRU step: gh GEMM (3 gates) + gate combine ----------------
// h_new = GRU(GI, h_prev); W rows [r;z;n], K = H. BM=64 rows, 64 h-cols/block.
__global__ __launch_bounds__(256) void gru_step_kernel(
    const float* __restrict__ hprev, const float* __restrict__ Whh,
    const float* __restrict__ bhh, const float* __restrict__ GI,
    float* __restrict__ hnew, int M, int H)
{
  __shared__ float As[32][68];
  __shared__ float Ws[32][196];
  const int tid = threadIdx.x;
  const int tx = tid & 15, ty = tid >> 4;
  const int m0 = blockIdx.x * 64;
  const int h0 = blockIdx.y * 64;
  const int lrow = tid >> 2;
  const int lk   = (tid & 3) * 8;
  const int K = H;
  float accR[4][4] = {}, accZ[4][4] = {}, accN[4][4] = {};

  for (int k0 = 0; k0 < K; k0 += 32){
    {
      const int m = m0 + lrow;
      float4 v0 = make_float4(0.f,0.f,0.f,0.f), v1 = v0;
      if (m < M){
        const float* src = &hprev[(size_t)m*H + k0 + lk];
        v0 = *(const float4*)src;
        v1 = *(const float4*)(src + 4);
      }
      As[lk+0][lrow]=v0.x; As[lk+1][lrow]=v0.y; As[lk+2][lrow]=v0.z; As[lk+3][lrow]=v0.w;
      As[lk+4][lrow]=v1.x; As[lk+5][lrow]=v1.y; As[lk+6][lrow]=v1.z; As[lk+7][lrow]=v1.w;
      #pragma unroll
      for (int g = 0; g < 3; ++g){
        const float* wsrc = &Whh[(size_t)(g*H + h0 + lrow)*K + k0 + lk];
        float4 w0 = *(const float4*)wsrc, w1 = *(const float4*)(wsrc + 4);
        Ws[lk+0][g*64+lrow]=w0.x; Ws[lk+1][g*64+lrow]=w0.y; Ws[lk+2][g*64+lrow]=w0.z; Ws[lk+3][g*64+lrow]=w0.w;
        Ws[lk+4][g*64+lrow]=w1.x; Ws[lk+5][g*64+lrow]=w1.y; Ws[lk+6][g*64+lrow]=w1.z; Ws[lk+7][g*64+lrow]=w1.w;
      }
    }
    __syncthreads();
    #pragma unroll
    for (int k = 0; k < 32; ++k){
      const float4 a  = *(const float4*)&As[k][ty*4];
      const float4 wr = *(const float4*)&Ws[k][      tx*4];
      const float4 wz = *(const float4*)&Ws[k][ 64 + tx*4];
      const float4 wn = *(const float4*)&Ws[k][128 + tx*4];
      const float av[4] = {a.x,a.y,a.z,a.w};
      const float rv[4] = {wr.x,wr.y,wr.z,wr.w};
      const float zv[4] = {wz.x,wz.y,wz.z,wz.w};
      const float nv[4] = {wn.x,wn.y,wn.z,wn.w};
      #pragma unroll
      for (int i = 0; i < 4; ++i)
        #pragma unroll
        for (int j = 0; j < 4; ++j){
          accR[i][j] = fmaf(av[i], rv[j], accR[i][j]);
          accZ[i][j] = fmaf(av[i], zv[j], accZ[i][j]);
          accN[i][j] = fmaf(av[i], nv[j], accN[i][j]);
        }
    }
    __syncthreads();
  }

  const int H3 = 3*H;
  const float4 br4 = *(const float4*)&bhh[      h0 + tx*4];
  const float4 bz4 = *(const float4*)&bhh[H   + h0 + tx*4];
  const float4 bn4 = *(const float4*)&bhh[2*H + h0 + tx*4];
  const float brv[4] = {br4.x,br4.y,br4.z,br4.w};
  const float bzv[4] = {bz4.x,bz4.y,bz4.z,bz4.w};
  const float bnv[4] = {bn4.x,bn4.y,bn4.z,bn4.w};

  #pragma unroll
  for (int i = 0; i < 4; ++i){
    const int m = m0 + ty*4 + i;
    if (m >= M) continue;
    const float* gi = &GI[(size_t)m*H3];
    const float4 hp4 = *(const float4*)&hprev[(size_t)m*H + h0 + tx*4];
    const float hpv[4] = {hp4.x,hp4.y,hp4.z,hp4.w};
    float ov[4];
    #pragma unroll
    for (int j = 0; j < 4; ++j){
      const int c = h0 + tx*4 + j;
      const float gr = gi[c]       + accR[i][j] + brv[j];
      const float gz = gi[H + c]   + accZ[i][j] + bzv[j];
      const float r  = sigmoidf_(gr);
      const float z  = sigmoidf_(gz);
      const float nn = tanhf(gi[2*H + c] + r*(accN[i][j] + bnv[j]));
      ov[j] = (1.0f - z)*nn + z*hpv[j];
    }
    float4 o; o.x=ov[0]; o.y=ov[1]; o.z=ov[2]; o.w=ov[3];
    *(float4*)&hnew[(size_t)m*H + h0 + tx*4] = o;
  }
}

// ---------------- graph conv: out[i] = bias + dis_i^2*h[i] + sum_e ew*h[row] ----------------
template<int H, bool RELU>
__global__ __launch_bounds__(256) void conv_kernel(
    const float* __restrict__ h, const int* __restrict__ perm,
    const float* __restrict__ ew, const int* __restrict__ off,
    const float* __restrict__ dis, const float* __restrict__ bias,
    float* __restrict__ out)
{
  const int i = blockIdx.x;
  const int f = threadIdx.x;
  const float d = dis[i];
  float acc = d*d*h[(size_t)i*H + f];
  const int s  = off[i];
  const int e2 = off[i+1];
  int e = s;
  for (; e + 4 <= e2; e += 4){
    const int   r0 = perm[e],   r1 = perm[e+1], r2 = perm[e+2], r3 = perm[e+3];
    const float w0 = ew[e],     w1 = ew[e+1],   w2 = ew[e+2],   w3 = ew[e+3];
    const float v0 = h[(size_t)r0*H + f];
    const float v1 = h[(size_t)r1*H + f];
    const float v2 = h[(size_t)r2*H + f];
    const float v3 = h[(size_t)r3*H + f];
    acc += w0*v0; acc += w1*v1; acc += w2*v2; acc += w3*v3;
  }
  for (; e < e2; ++e) acc += ew[e]*h[(size_t)perm[e]*H + f];
  acc += bias[f];
  if (RELU) acc = fmaxf(acc, 0.0f);
  out[(size_t)i*H + f] = acc;
}

// ---------------- final dense: logits[j] += dot(lin_W[j], flat) ----------------
__global__ __launch_bounds__(256) void dense_kernel(const float* __restrict__ flat,
    const float* __restrict__ linW, float* __restrict__ logits)
{
  const int j   = blockIdx.x;
  const int tid = threadIdx.x;
  const int Q4  = FLATSZ/4;                  // 320000
  const int CH4 = Q4/16;                     // 20000 (gridDim.y == 16)
  const int s4  = blockIdx.y*CH4;
  const int e4  = s4 + CH4;
  const float4* w4 = (const float4*)&linW[(size_t)j*FLATSZ];
  const float4* f4 = (const float4*)flat;
  float part = 0.0f;
  for (int i = s4 + tid; i < e4; i += 256){
    const float4 a = w4[i];
    const float4 b = f4[i];
    part += a.x*b.x + a.y*b.y + a.z*b.z + a.w*b.w;
  }
  __shared__ float red[256];
  red[tid] = part; __syncthreads();
  for (int s = 128; s > 0; s >>= 1){
    if (tid < s) red[tid] += red[tid + s];
    __syncthreads();
  }
  if (tid == 0) atomicAdd(&logits[j], red[0]);
}

__global__ __launch_bounds__(128) void softmax_kernel(const float* __restrict__ logits,
    const float* __restrict__ linb, float* __restrict__ out)
{
  __shared__ float red[128];
  const int tid = threadIdx.x;
  const float v = (tid < OUTD) ? logits[tid] + linb[tid] : -INFINITY;
  red[tid] = v; __syncthreads();
  for (int s = 64; s > 0; s >>= 1){
    if (tid < s) red[tid] = fmaxf(red[tid], red[tid + s]);
    __syncthreads();
  }
  const float mx = red[0]; __syncthreads();
  const float e = (tid < OUTD) ? expf(v - mx) : 0.0f;
  red[tid] = e; __syncthreads();
  for (int s = 64; s > 0; s >>= 1){
    if (tid < s) red[tid] += red[tid + s];
    __syncthreads();
  }
  const float inv = 1.0f/red[0];
  if (tid < OUTD) out[tid] = e*inv;
}

// ---------------- launch ----------------

extern "C" void kernel_launch(void* const* d_in, const int* in_sizes, int n_in,
                              void* d_out, int out_size, void* d_ws, size_t ws_size,
                              hipStream_t stream)
{
  const float* x     = (const float*)d_in[0];
  const int*   ei    = (const int*)  d_in[1];
  const float* W_ih1 = (const float*)d_in[2];
  const float* W_hh1 = (const float*)d_in[3];
  const float* b_ih1 = (const float*)d_in[4];
  const float* b_hh1 = (const float*)d_in[5];
  const float* bias1 = (const float*)d_in[6];
  const float* W_ih2 = (const float*)d_in[7];
  const float* W_hh2 = (const float*)d_in[8];
  const float* b_ih2 = (const float*)d_in[9];
  const float* b_hh2 = (const float*)d_in[10];
  const float* bias2 = (const float*)d_in[11];
  const float* lin_W = (const float*)d_in[12];
  const float* lin_b = (const float*)d_in[13];
  float* out = (float*)d_out;
  const int E = in_sizes[1]/2;
  (void)n_in; (void)out_size; (void)ws_size;

  char* p = (char*)d_ws;
  auto alloc = [&](size_t bytes)->void* {
    void* r = (void*)p;
    p += (bytes + 255) & ~(size_t)255;
    return r;
  };
  int*   cnt    = (int*)  alloc((size_t)NN*4);
  int*   cursor = (int*)  alloc((size_t)NN*4);
  int*   offs   = (int*)  alloc((size_t)(NN+1)*4);
  float* dis    = (float*)alloc((size_t)NN*4);
  int*   perm   = (int*)  alloc((size_t)E*4);
  float* ew     = (float*)alloc((size_t)E*4);
  float* gi1    = (float*)alloc((size_t)NN*768*4);
  float* gi2    = (float*)alloc((size_t)NN*384*4);
  float* h1a    = (float*)alloc((size_t)NN*H1C*4);
  float* h1b    = (float*)alloc((size_t)NN*H1C*4);
  float* x2t    = (float*)alloc((size_t)NN*H1C*4);
  float* h2a    = (float*)alloc((size_t)NN*H2C*4);
  float* h2b    = (float*)alloc((size_t)NN*H2C*4);
  float* out2   = (float*)alloc((size_t)NN*H2C*4);
  float* logits = (float*)alloc((size_t)OUTD*4);

  // graph preprocessing (per call — deterministic up to atomic edge order; fp32 noise << threshold)
  init_kernel   <<<(NN+255)/256, 256, 0, stream>>>(cnt, cursor, logits, NN);
  count_kernel  <<<(E+255)/256, 256, 0, stream>>>(ei, cnt, E);
  dis_kernel    <<<(NN+255)/256, 256, 0, stream>>>(cnt, dis, NN);
  scan_kernel   <<<1, 256, 0, stream>>>(cnt, offs, NN);
  scatter_kernel<<<(E+255)/256, 256, 0, stream>>>(ei, dis, offs, cursor, perm, ew, E);

  zero_f32_kernel<<<(NN*H1C+255)/256, 256, 0, stream>>>(h1a, NN*H1C);
  zero_f32_kernel<<<(NN*H2C+255)/256, 256, 0, stream>>>(h2a, NN*H2C);

  float* h1cur = h1a; float* h1nxt = h1b;
  float* h2cur = h2a; float* h2nxt = h2b;
  const int MB = (NN + 63)/64;   // 157

  for (int t = 0; t < TT; ++t){
    // GI1 = x[t] @ W_ih1^T + b_ih1
    gemm_bias_kernel<<<dim3(MB, 768/64), 256, 0, stream>>>(
        x + (size_t)t*NN*DIN, W_ih1, b_ih1, gi1, NN, 768, DIN);
    // h1 = GRUstep(GI1, h1)
    gru_step_kernel<<<dim3(MB, H1C/64), 256, 0, stream>>>(
        h1cur, W_hh1, b_hh1, gi1, h1nxt, NN, H1C);
    // x2t = relu(conv(h1) + bias1)
    conv_kernel<H1C, true><<<NN, H1C, 0, stream>>>(h1nxt, perm, ew, offs, dis, bias1, x2t);
    // GI2 = x2t @ W_ih2^T + b_ih2
    gemm_bias_kernel<<<dim3(MB, 384/64), 256, 0, stream>>>(
        x2t, W_ih2, b_ih2, gi2, NN, 384, H1C);
    // h2 = GRUstep(GI2, h2)
    gru_step_kernel<<<dim3(MB, H2C/64), 256, 0, stream>>>(
        h2cur, W_hh2, b_hh2, gi2, h2nxt, NN, H2C);

    float* tmp;
    tmp = h1cur; h1cur = h1nxt; h1nxt = tmp;
    tmp = h2cur; h2cur = h2nxt; h2nxt = tmp;
  }

  // out2 = conv(h2[T-1]) + bias2  (no relu)
  conv_kernel<H2C, false><<<NN, H2C, 0, stream>>>(h2cur, perm, ew, offs, dis, bias2, out2);
  // logits
  dense_kernel<<<dim3(OUTD, 16), 256, 0, stream>>>(out2, lin_W, logits);
  // softmax -> d_out
  softmax_kernel<<<1, 128, 0, stream>>>(logits, lin_b, out);
}

// Round 2
// 2624.157 us; speedup vs baseline: 1.9502x; 1.9502x over previous
//
#include <hip/hip_runtime.h>
#include <math.h>

#define TT   24
#define NN   10000
#define DIN  128
#define H1C  256
#define H2C  128
#define OUTD 100
#define FLATSZ (NN*H2C)

typedef _Float16 f16;
typedef _Float16 f16x2 __attribute__((ext_vector_type(2)));
typedef _Float16 f16x4 __attribute__((ext_vector_type(4)));
typedef _Float16 f16x8 __attribute__((ext_vector_type(8)));
typedef float    f32x4 __attribute__((ext_vector_type(4)));

__device__ __forceinline__ float sigmoidf_(float x){ return 1.0f/(1.0f+expf(-x)); }

// ---------------- small utility kernels ----------------

__global__ __launch_bounds__(256) void zero16_kernel(uint4* __restrict__ p, int n16){
  int i = blockIdx.x*256 + threadIdx.x;
  if (i < n16) p[i] = make_uint4(0u,0u,0u,0u);
}

__global__ __launch_bounds__(256) void cast_f16_kernel(const float4* __restrict__ in,
                                                       f16x4* __restrict__ out, int n4){
  int i = blockIdx.x*256 + threadIdx.x;
  if (i < n4){
    float4 v = in[i];
    f16x4 o; o[0]=(f16)v.x; o[1]=(f16)v.y; o[2]=(f16)v.z; o[3]=(f16)v.w;
    out[i] = o;
  }
}

__global__ __launch_bounds__(256) void init_kernel(int* __restrict__ cnt, int* __restrict__ cursor,
                                                   float* __restrict__ logits, int n){
  int i = blockIdx.x*256 + threadIdx.x;
  if (i < n){ cnt[i] = 0; cursor[i] = 0; }
  if (i < OUTD) logits[i] = 0.0f;
}

__global__ __launch_bounds__(256) void count_kernel(const int* __restrict__ ei, int* __restrict__ cnt, int E){
  int e = blockIdx.x*256 + threadIdx.x;
  if (e < E) atomicAdd(&cnt[ei[E + e]], 1);
}

__global__ __launch_bounds__(256) void dis_kernel(const int* __restrict__ cnt, float* __restrict__ dis, int n){
  int i = blockIdx.x*256 + threadIdx.x;
  if (i < n) dis[i] = rsqrtf((float)(cnt[i] + 1));   // +1 self-loop
}

__global__ __launch_bounds__(256) void scan_kernel(const int* __restrict__ cnt, int* __restrict__ off, int n){
  __shared__ int sums[256];
  const int tid = threadIdx.x;
  const int CH  = 40;                  // 256*40 = 10240 >= NN
  const int base = tid*CH;
  int s = 0;
  for (int i = 0; i < CH; ++i){ int idx = base + i; if (idx < n) s += cnt[idx]; }
  sums[tid] = s; __syncthreads();
  for (int d = 1; d < 256; d <<= 1){
    int v = (tid >= d) ? sums[tid - d] : 0;
    __syncthreads();
    sums[tid] += v;
    __syncthreads();
  }
  int run = (tid == 0) ? 0 : sums[tid - 1];
  for (int i = 0; i < CH; ++i){
    int idx = base + i;
    if (idx < n){ off[idx] = run; run += cnt[idx]; }
  }
  if (tid == 0) off[n] = sums[255];
}

__global__ __launch_bounds__(256) void scatter_kernel(const int* __restrict__ ei, const float* __restrict__ dis,
                                                      const int* __restrict__ off, int* __restrict__ cursor,
                                                      int* __restrict__ perm, float* __restrict__ ew, int E){
  int e = blockIdx.x*256 + threadIdx.x;
  if (e < E){
    int r = ei[e];
    int c = ei[E + e];
    int pos = off[c] + atomicAdd(&cursor[c], 1);
    perm[pos] = r;
    ew[pos]   = dis[r]*dis[c];
  }
}

// ---------------- MFMA GEMM: C[m][n] = sum_k A[m][k]*W[n][k], all f16 in, f16 out ----------------
// Block 256 thr = 4 waves (2Mx2N), wave tile 64x64, block tile 128x128. N must be multiple of 128.
template<int K>
__global__ __launch_bounds__(256) void gemm_f16_kernel(
    const f16* __restrict__ A, const f16* __restrict__ W,
    f16* __restrict__ C, int M, int N)
{
  const int lane = threadIdx.x & 63;
  const int wave = threadIdx.x >> 6;
  const int wm = wave >> 1, wc = wave & 1;
  const int m_base = blockIdx.x*128 + wm*64;
  const int n_base = blockIdx.y*128 + wc*64;
  const int lr = lane & 15;          // A row / B col / C col within fragment
  const int lk = (lane >> 4) * 8;    // k sub-chunk
  f32x4 acc[4][4] = {};
  const f16* aptr[4]; const f16* bptr[4];
  #pragma unroll
  for (int mi = 0; mi < 4; ++mi){
    int r = m_base + mi*16 + lr; if (r >= M) r = M - 1;
    aptr[mi] = A + (size_t)r*K + lk;
  }
  #pragma unroll
  for (int ci = 0; ci < 4; ++ci){
    int c = n_base + ci*16 + lr;
    bptr[ci] = W + (size_t)c*K + lk;
  }
  #pragma unroll
  for (int k0 = 0; k0 < K; k0 += 32){
    f16x8 a[4], b[4];
    #pragma unroll
    for (int mi = 0; mi < 4; ++mi) a[mi] = *(const f16x8*)(aptr[mi] + k0);
    #pragma unroll
    for (int ci = 0; ci < 4; ++ci) b[ci] = *(const f16x8*)(bptr[ci] + k0);
    #pragma unroll
    for (int mi = 0; mi < 4; ++mi)
      #pragma unroll
      for (int ci = 0; ci < 4; ++ci)
        acc[mi][ci] = __builtin_amdgcn_mfma_f32_16x16x32_f16(a[mi], b[ci], acc[mi][ci], 0, 0, 0);
  }
  const int r0 = (lane >> 4)*4;     // C/D: row=(lane>>4)*4+reg, col=lane&15
  #pragma unroll
  for (int mi = 0; mi < 4; ++mi){
    #pragma unroll
    for (int r = 0; r < 4; ++r){
      const int row = m_base + mi*16 + r0 + r;
      if (row < M){
        #pragma unroll
        for (int ci = 0; ci < 4; ++ci)
          C[(size_t)row*N + n_base + ci*16 + lr] = (f16)acc[mi][ci][r];
      }
    }
  }
}

// ---------------- fused GRU step (MFMA): gh = h @ Whh^T (3 gates) + gate combine ----------------
// Wave tile 32 rows x 32 cols x 3 gates; block 2x2 waves = 64x64. grid.y = H/64.
template<int H>
__global__ __launch_bounds__(256) void gru_mfma_kernel(
    const f16* __restrict__ h16, const float* __restrict__ h32,
    const f16* __restrict__ W16,            // (3H, H) row-major
    const f16* __restrict__ GI,             // (M, 3H) no bias
    const float* __restrict__ bih, const float* __restrict__ bhh,  // (3H)
    float* __restrict__ o32, f16* __restrict__ o16, int M)
{
  const int lane = threadIdx.x & 63;
  const int wave = threadIdx.x >> 6;
  const int wm = wave >> 1, wc = wave & 1;
  const int m_base = blockIdx.x*64 + wm*32;
  const int c_base = blockIdx.y*64 + wc*32;
  const int lr = lane & 15;
  const int lk = (lane >> 4)*8;
  f32x4 acc[2][2][3] = {};
  const f16* aptr[2]; const f16* bptr[2][3];
  #pragma unroll
  for (int mi = 0; mi < 2; ++mi){
    int r = m_base + mi*16 + lr; if (r >= M) r = M - 1;
    aptr[mi] = h16 + (size_t)r*H + lk;
  }
  #pragma unroll
  for (int ci = 0; ci < 2; ++ci)
    #pragma unroll
    for (int g = 0; g < 3; ++g){
      int c = g*H + c_base + ci*16 + lr;
      bptr[ci][g] = W16 + (size_t)c*H + lk;
    }
  #pragma unroll
  for (int k0 = 0; k0 < H; k0 += 32){
    f16x8 a[2], b[2][3];
    #pragma unroll
    for (int mi = 0; mi < 2; ++mi) a[mi] = *(const f16x8*)(aptr[mi] + k0);
    #pragma unroll
    for (int ci = 0; ci < 2; ++ci)
      #pragma unroll
      for (int g = 0; g < 3; ++g) b[ci][g] = *(const f16x8*)(bptr[ci][g] + k0);
    #pragma unroll
    for (int mi = 0; mi < 2; ++mi)
      #pragma unroll
      for (int ci = 0; ci < 2; ++ci)
        #pragma unroll
        for (int g = 0; g < 3; ++g)
          acc[mi][ci][g] = __builtin_amdgcn_mfma_f32_16x16x32_f16(a[mi], b[ci][g], acc[mi][ci][g], 0, 0, 0);
  }
  const int r0 = (lane >> 4)*4;
  #pragma unroll
  for (int mi = 0; mi < 2; ++mi){
    #pragma unroll
    for (int r = 0; r < 4; ++r){
      const int row = m_base + mi*16 + r0 + r;
      if (row >= M) continue;
      const f16* gi = GI + (size_t)row*3*H;
      #pragma unroll
      for (int ci = 0; ci < 2; ++ci){
        const int col = c_base + ci*16 + lr;
        const float gr = (float)gi[col]     + bih[col]     + acc[mi][ci][0][r] + bhh[col];
        const float gz = (float)gi[H+col]   + bih[H+col]   + acc[mi][ci][1][r] + bhh[H+col];
        const float rg = sigmoidf_(gr);
        const float zg = sigmoidf_(gz);
        const float ng = tanhf((float)gi[2*H+col] + bih[2*H+col] + rg*(acc[mi][ci][2][r] + bhh[2*H+col]));
        const float hp = h32[(size_t)row*H + col];
        const float hv = (1.0f - zg)*ng + zg*hp;
        o32[(size_t)row*H + col] = hv;
        o16[(size_t)row*H + col] = (f16)hv;
      }
    }
  }
}

// ---------------- graph conv (f16 gather, fp32 accumulate) ----------------
// conv1: H=256, 128 threads/node, relu, f16 out
__global__ __launch_bounds__(128) void conv1_kernel(
    const f16* __restrict__ h, const int* __restrict__ perm,
    const float* __restrict__ ew, const int* __restrict__ off,
    const float* __restrict__ dis, const float* __restrict__ bias,
    f16* __restrict__ out)
{
  const int i = blockIdx.x;
  const int f = threadIdx.x;            // 0..127 (half2 index)
  const f16x2* hp = (const f16x2*)h;
  const float d = dis[i];
  const f16x2 sv = hp[(size_t)i*128 + f];
  float a0 = d*d*(float)sv[0];
  float a1 = d*d*(float)sv[1];
  int e = off[i]; const int e2 = off[i+1];
  for (; e + 4 <= e2; e += 4){
    const int   r0 = perm[e],   r1 = perm[e+1], r2 = perm[e+2], r3 = perm[e+3];
    const float w0 = ew[e],     w1 = ew[e+1],   w2 = ew[e+2],   w3 = ew[e+3];
    const f16x2 v0 = hp[(size_t)r0*128 + f];
    const f16x2 v1 = hp[(size_t)r1*128 + f];
    const f16x2 v2 = hp[(size_t)r2*128 + f];
    const f16x2 v3 = hp[(size_t)r3*128 + f];
    a0 += w0*(float)v0[0] + w1*(float)v1[0] + w2*(float)v2[0] + w3*(float)v3[0];
    a1 += w0*(float)v0[1] + w1*(float)v1[1] + w2*(float)v2[1] + w3*(float)v3[1];
  }
  for (; e < e2; ++e){
    const int r = perm[e]; const float w = ew[e];
    const f16x2 v = hp[(size_t)r*128 + f];
    a0 += w*(float)v[0]; a1 += w*(float)v[1];
  }
  const float2 bb = ((const float2*)bias)[f];
  a0 = fmaxf(a0 + bb.x, 0.0f);
  a1 = fmaxf(a1 + bb.y, 0.0f);
  f16x2 o; o[0] = (f16)a0; o[1] = (f16)a1;
  ((f16x2*)out)[(size_t)i*128 + f] = o;
}

// conv2: H=128, 64 threads/node, no relu, fp32 out
__global__ __launch_bounds__(64) void conv2_kernel(
    const f16* __restrict__ h, const int* __restrict__ perm,
    const float* __restrict__ ew, const int* __restrict__ off,
    const float* __restrict__ dis, const float* __restrict__ bias,
    float* __restrict__ out)
{
  const int i = blockIdx.x;
  const int f = threadIdx.x;            // 0..63 (half2 index)
  const f16x2* hp = (const f16x2*)h;
  const float d = dis[i];
  const f16x2 sv = hp[(size_t)i*64 + f];
  float a0 = d*d*(float)sv[0];
  float a1 = d*d*(float)sv[1];
  int e = off[i]; const int e2 = off[i+1];
  for (; e + 4 <= e2; e += 4){
    const int   r0 = perm[e],   r1 = perm[e+1], r2 = perm[e+2], r3 = perm[e+3];
    const float w0 = ew[e],     w1 = ew[e+1],   w2 = ew[e+2],   w3 = ew[e+3];
    const f16x2 v0 = hp[(size_t)r0*64 + f];
    const f16x2 v1 = hp[(size_t)r1*64 + f];
    const f16x2 v2 = hp[(size_t)r2*64 + f];
    const f16x2 v3 = hp[(size_t)r3*64 + f];
    a0 += w0*(float)v0[0] + w1*(float)v1[0] + w2*(float)v2[0] + w3*(float)v3[0];
    a1 += w0*(float)v0[1] + w1*(float)v1[1] + w2*(float)v2[1] + w3*(float)v3[1];
  }
  for (; e < e2; ++e){
    const int r = perm[e]; const float w = ew[e];
    const f16x2 v = hp[(size_t)r*64 + f];
    a0 += w*(float)v[0]; a1 += w*(float)v[1];
  }
  const float2 bb = ((const float2*)bias)[f];
  ((float2*)out)[(size_t)i*64 + f] = make_float2(a0 + bb.x, a1 + bb.y);
}

// ---------------- final dense + softmax ----------------
__global__ __launch_bounds__(256) void dense_kernel(const float* __restrict__ flat,
    const float* __restrict__ linW, float* __restrict__ logits)
{
  const int j   = blockIdx.x;
  const int tid = threadIdx.x;
  const int Q4  = FLATSZ/4;                  // 320000
  const int CH4 = Q4/16;                     // 20000 (gridDim.y == 16)
  const int s4  = blockIdx.y*CH4;
  const int e4  = s4 + CH4;
  const float4* w4 = (const float4*)&linW[(size_t)j*FLATSZ];
  const float4* f4 = (const float4*)flat;
  float part = 0.0f;
  for (int i = s4 + tid; i < e4; i += 256){
    const float4 a = w4[i];
    const float4 b = f4[i];
    part += a.x*b.x + a.y*b.y + a.z*b.z + a.w*b.w;
  }
  __shared__ float red[256];
  red[tid] = part; __syncthreads();
  for (int s = 128; s > 0; s >>= 1){
    if (tid < s) red[tid] += red[tid + s];
    __syncthreads();
  }
  if (tid == 0) atomicAdd(&logits[j], red[0]);
}

__global__ __launch_bounds__(128) void softmax_kernel(const float* __restrict__ logits,
    const float* __restrict__ linb, float* __restrict__ out)
{
  __shared__ float red[128];
  const int tid = threadIdx.x;
  const float v = (tid < OUTD) ? logits[tid] + linb[tid] : -INFINITY;
  red[tid] = v; __syncthreads();
  for (int s = 64; s > 0; s >>= 1){
    if (tid < s) red[tid] = fmaxf(red[tid], red[tid + s]);
    __syncthreads();
  }
  const float mx = red[0]; __syncthreads();
  const float e = (tid < OUTD) ? expf(v - mx) : 0.0f;
  red[tid] = e; __syncthreads();
  for (int s = 64; s > 0; s >>= 1){
    if (tid < s) red[tid] += red[tid + s];
    __syncthreads();
  }
  const float inv = 1.0f/red[0];
  if (tid < OUTD) out[tid] = e*inv;
}

// ---------------- launch ----------------

extern "C" void kernel_launch(void* const* d_in, const int* in_sizes, int n_in,
                              void* d_out, int out_size, void* d_ws, size_t ws_size,
                              hipStream_t stream)
{
  const float* x     = (const float*)d_in[0];
  const int*   ei    = (const int*)  d_in[1];
  const float* W_ih1 = (const float*)d_in[2];
  const float* W_hh1 = (const float*)d_in[3];
  const float* b_ih1 = (const float*)d_in[4];
  const float* b_hh1 = (const float*)d_in[5];
  const float* bias1 = (const float*)d_in[6];
  const float* W_ih2 = (const float*)d_in[7];
  const float* W_hh2 = (const float*)d_in[8];
  const float* b_ih2 = (const float*)d_in[9];
  const float* b_hh2 = (const float*)d_in[10];
  const float* bias2 = (const float*)d_in[11];
  const float* lin_W = (const float*)d_in[12];
  const float* lin_b = (const float*)d_in[13];
  float* out = (float*)d_out;
  const int E = in_sizes[1]/2;
  (void)n_in; (void)out_size; (void)ws_size;

  char* p = (char*)d_ws;
  auto alloc = [&](size_t bytes)->void* {
    void* r = (void*)p;
    p += (bytes + 255) & ~(size_t)255;
    return r;
  };
  int*   cnt    = (int*)  alloc((size_t)NN*4);
  int*   cursor = (int*)  alloc((size_t)NN*4);
  int*   offs   = (int*)  alloc((size_t)(NN+1)*4);
  float* dis    = (float*)alloc((size_t)NN*4);
  int*   perm   = (int*)  alloc((size_t)E*4);
  float* ew     = (float*)alloc((size_t)E*4);
  f16*   xf16   = (f16*)  alloc((size_t)TT*NN*DIN*2);
  f16*   gi1    = (f16*)  alloc((size_t)TT*NN*(3*H1C)*2);
  f16*   gi2    = (f16*)  alloc((size_t)NN*(3*H2C)*2);
  float* h1f32a = (float*)alloc((size_t)NN*H1C*4);
  float* h1f32b = (float*)alloc((size_t)NN*H1C*4);
  f16*   h1f16a = (f16*)  alloc((size_t)NN*H1C*2);
  f16*   h1f16b = (f16*)  alloc((size_t)NN*H1C*2);
  float* h2f32a = (float*)alloc((size_t)NN*H2C*4);
  float* h2f32b = (float*)alloc((size_t)NN*H2C*4);
  f16*   h2f16a = (f16*)  alloc((size_t)NN*H2C*2);
  f16*   h2f16b = (f16*)  alloc((size_t)NN*H2C*2);
  f16*   x2t    = (f16*)  alloc((size_t)NN*H1C*2);
  float* out2   = (float*)alloc((size_t)NN*H2C*4);
  f16*   wih1h  = (f16*)  alloc((size_t)3*H1C*DIN*2);
  f16*   whh1h  = (f16*)  alloc((size_t)3*H1C*H1C*2);
  f16*   wih2h  = (f16*)  alloc((size_t)3*H2C*H1C*2);
  f16*   whh2h  = (f16*)  alloc((size_t)3*H2C*H2C*2);
  float* logits = (float*)alloc((size_t)OUTD*4);

  // ---- graph preprocessing ----
  init_kernel   <<<(NN+255)/256, 256, 0, stream>>>(cnt, cursor, logits, NN);
  count_kernel  <<<(E+255)/256, 256, 0, stream>>>(ei, cnt, E);
  dis_kernel    <<<(NN+255)/256, 256, 0, stream>>>(cnt, dis, NN);
  scan_kernel   <<<1, 256, 0, stream>>>(cnt, offs, NN);
  scatter_kernel<<<(E+255)/256, 256, 0, stream>>>(ei, dis, offs, cursor, perm, ew, E);

  // ---- zero h state (fp32 + fp16 mirrors) ----
  zero16_kernel<<<((NN*H1C*4/16)+255)/256, 256, 0, stream>>>((uint4*)h1f32a, NN*H1C*4/16);
  zero16_kernel<<<((NN*H1C*2/16)+255)/256, 256, 0, stream>>>((uint4*)h1f16a, NN*H1C*2/16);
  zero16_kernel<<<((NN*H2C*4/16)+255)/256, 256, 0, stream>>>((uint4*)h2f32a, NN*H2C*4/16);
  zero16_kernel<<<((NN*H2C*2/16)+255)/256, 256, 0, stream>>>((uint4*)h2f16a, NN*H2C*2/16);

  // ---- fp16 casts: x and the four GRU weight matrices ----
  cast_f16_kernel<<<((TT*NN*DIN/4)+255)/256, 256, 0, stream>>>((const float4*)x, (f16x4*)xf16, TT*NN*DIN/4);
  cast_f16_kernel<<<((3*H1C*DIN/4)+255)/256, 256, 0, stream>>>((const float4*)W_ih1, (f16x4*)wih1h, 3*H1C*DIN/4);
  cast_f16_kernel<<<((3*H1C*H1C/4)+255)/256, 256, 0, stream>>>((const float4*)W_hh1, (f16x4*)whh1h, 3*H1C*H1C/4);
  cast_f16_kernel<<<((3*H2C*H1C/4)+255)/256, 256, 0, stream>>>((const float4*)W_ih2, (f16x4*)wih2h, 3*H2C*H1C/4);
  cast_f16_kernel<<<((3*H2C*H2C/4)+255)/256, 256, 0, stream>>>((const float4*)W_hh2, (f16x4*)whh2h, 3*H2C*H2C/4);

  // ---- GI1 for all timesteps in one big GEMM: (TT*NN, 128) x (768, 128)^T ----
  gemm_f16_kernel<DIN><<<dim3(TT*NN/128, (3*H1C)/128), 256, 0, stream>>>(xf16, wih1h, gi1, TT*NN, 3*H1C);

  float* h1c32 = h1f32a; float* h1n32 = h1f32b;
  f16*   h1c16 = h1f16a; f16*   h1n16 = h1f16b;
  float* h2c32 = h2f32a; float* h2n32 = h2f32b;
  f16*   h2c16 = h2f16a; f16*   h2n16 = h2f16b;
  const int MB64 = (NN + 63)/64;     // 157
  const int MB128 = (NN + 127)/128;  // 79

  for (int t = 0; t < TT; ++t){
    gru_mfma_kernel<H1C><<<dim3(MB64, H1C/64), 256, 0, stream>>>(
        h1c16, h1c32, whh1h, gi1 + (size_t)t*NN*(3*H1C), b_ih1, b_hh1, h1n32, h1n16, NN);
    conv1_kernel<<<NN, 128, 0, stream>>>(h1n16, perm, ew, offs, dis, bias1, x2t);
    gemm_f16_kernel<H1C><<<dim3(MB128, (3*H2C)/128), 256, 0, stream>>>(x2t, wih2h, gi2, NN, 3*H2C);
    gru_mfma_kernel<H2C><<<dim3(MB64, H2C/64), 256, 0, stream>>>(
        h2c16, h2c32, whh2h, gi2, b_ih2, b_hh2, h2n32, h2n16, NN);

    float* tf; f16* th;
    tf = h1c32; h1c32 = h1n32; h1n32 = tf;
    th = h1c16; h1c16 = h1n16; h1n16 = th;
    tf = h2c32; h2c32 = h2n32; h2n32 = tf;
    th = h2c16; h2c16 = h2n16; h2n16 = th;
  }

  conv2_kernel<<<NN, 64, 0, stream>>>(h2c16, perm, ew, offs, dis, bias2, out2);
  dense_kernel<<<dim3(OUTD, 16), 256, 0, stream>>>(out2, lin_W, logits);
  softmax_kernel<<<1, 128, 0, stream>>>(logits, lin_b, out);
}

// Round 3
// 2567.746 us; speedup vs baseline: 1.9930x; 1.0220x over previous
//
#include <hip/hip_runtime.h>
#include <math.h>

#define TT   24
#define NN   10000
#define DIN  128
#define H1C  256
#define H2C  128
#define OUTD 100
#define FLATSZ (NN*H2C)

typedef _Float16 f16;
typedef _Float16 f16x2 __attribute__((ext_vector_type(2)));
typedef _Float16 f16x4 __attribute__((ext_vector_type(4)));
typedef _Float16 f16x8 __attribute__((ext_vector_type(8)));
typedef float    f32x4 __attribute__((ext_vector_type(4)));

__device__ __forceinline__ float sigmoidf_(float x){ return 1.0f/(1.0f+expf(-x)); }

// ---------------- small utility kernels ----------------

__global__ __launch_bounds__(256) void zero16_kernel(uint4* __restrict__ p, int n16){
  int i = blockIdx.x*256 + threadIdx.x;
  if (i < n16) p[i] = make_uint4(0u,0u,0u,0u);
}

__global__ __launch_bounds__(256) void cast_f16_kernel(const float4* __restrict__ in,
                                                       f16x4* __restrict__ out, int n4){
  int i = blockIdx.x*256 + threadIdx.x;
  if (i < n4){
    float4 v = in[i];
    f16x4 o; o[0]=(f16)v.x; o[1]=(f16)v.y; o[2]=(f16)v.z; o[3]=(f16)v.w;
    out[i] = o;
  }
}

__global__ __launch_bounds__(256) void init_kernel(int* __restrict__ cnt, int* __restrict__ cursor,
                                                   float* __restrict__ logits, int n){
  int i = blockIdx.x*256 + threadIdx.x;
  if (i < n){ cnt[i] = 0; cursor[i] = 0; }
  if (i < OUTD) logits[i] = 0.0f;
}

__global__ __launch_bounds__(256) void count_kernel(const int* __restrict__ ei, int* __restrict__ cnt, int E){
  int e = blockIdx.x*256 + threadIdx.x;
  if (e < E) atomicAdd(&cnt[ei[E + e]], 1);
}

__global__ __launch_bounds__(256) void dis_kernel(const int* __restrict__ cnt, float* __restrict__ dis, int n){
  int i = blockIdx.x*256 + threadIdx.x;
  if (i < n) dis[i] = rsqrtf((float)(cnt[i] + 1));   // +1 self-loop
}

__global__ __launch_bounds__(256) void scan_kernel(const int* __restrict__ cnt, int* __restrict__ off, int n){
  __shared__ int sums[256];
  const int tid = threadIdx.x;
  const int CH  = 40;                  // 256*40 = 10240 >= NN
  const int base = tid*CH;
  int s = 0;
  for (int i = 0; i < CH; ++i){ int idx = base + i; if (idx < n) s += cnt[idx]; }
  sums[tid] = s; __syncthreads();
  for (int d = 1; d < 256; d <<= 1){
    int v = (tid >= d) ? sums[tid - d] : 0;
    __syncthreads();
    sums[tid] += v;
    __syncthreads();
  }
  int run = (tid == 0) ? 0 : sums[tid - 1];
  for (int i = 0; i < CH; ++i){
    int idx = base + i;
    if (idx < n){ off[idx] = run; run += cnt[idx]; }
  }
  if (tid == 0) off[n] = sums[255];
}

__global__ __launch_bounds__(256) void scatter_kernel(const int* __restrict__ ei, const float* __restrict__ dis,
                                                      const int* __restrict__ off, int* __restrict__ cursor,
                                                      int* __restrict__ perm, float* __restrict__ ew, int E){
  int e = blockIdx.x*256 + threadIdx.x;
  if (e < E){
    int r = ei[e];
    int c = ei[E + e];
    int pos = off[c] + atomicAdd(&cursor[c], 1);
    perm[pos] = r;
    ew[pos]   = dis[r]*dis[c];
  }
}

// ---------------- MFMA GEMM, fp32 A (in-register cvt): C = A @ W^T, f16 out ----------------
// Block 256 thr = 4 waves (2Mx2N), wave 64x64, block 128x128. M,N multiples of 128 assumed OK w/ clamp.
template<int K>
__global__ __launch_bounds__(256) void gemm_f32a_kernel(
    const float* __restrict__ A, const f16* __restrict__ W,
    f16* __restrict__ C, int M, int N)
{
  const int lane = threadIdx.x & 63;
  const int wave = threadIdx.x >> 6;
  const int wm = wave >> 1, wc = wave & 1;
  const int m_base = blockIdx.x*128 + wm*64;
  const int n_base = blockIdx.y*128 + wc*64;
  const int lr = lane & 15;
  const int lk = (lane >> 4) * 8;
  f32x4 acc[4][4] = {};
  const float* aptr[4]; const f16* bptr[4];
  #pragma unroll
  for (int mi = 0; mi < 4; ++mi){
    int r = m_base + mi*16 + lr; if (r >= M) r = M - 1;
    aptr[mi] = A + (size_t)r*K + lk;
  }
  #pragma unroll
  for (int ci = 0; ci < 4; ++ci){
    int c = n_base + ci*16 + lr;
    bptr[ci] = W + (size_t)c*K + lk;
  }
  #pragma unroll
  for (int k0 = 0; k0 < K; k0 += 32){
    f16x8 a[4], b[4];
    #pragma unroll
    for (int mi = 0; mi < 4; ++mi){
      const float4 v0 = *(const float4*)(aptr[mi] + k0);
      const float4 v1 = *(const float4*)(aptr[mi] + k0 + 4);
      f16x8 t;
      t[0]=(f16)v0.x; t[1]=(f16)v0.y; t[2]=(f16)v0.z; t[3]=(f16)v0.w;
      t[4]=(f16)v1.x; t[5]=(f16)v1.y; t[6]=(f16)v1.z; t[7]=(f16)v1.w;
      a[mi] = t;
    }
    #pragma unroll
    for (int ci = 0; ci < 4; ++ci) b[ci] = *(const f16x8*)(bptr[ci] + k0);
    #pragma unroll
    for (int mi = 0; mi < 4; ++mi)
      #pragma unroll
      for (int ci = 0; ci < 4; ++ci)
        acc[mi][ci] = __builtin_amdgcn_mfma_f32_16x16x32_f16(a[mi], b[ci], acc[mi][ci], 0, 0, 0);
  }
  const int r0 = (lane >> 4)*4;     // C/D: row=(lane>>4)*4+reg, col=lane&15
  #pragma unroll
  for (int mi = 0; mi < 4; ++mi){
    #pragma unroll
    for (int r = 0; r < 4; ++r){
      const int row = m_base + mi*16 + r0 + r;
      if (row < M){
        #pragma unroll
        for (int ci = 0; ci < 4; ++ci)
          C[(size_t)row*N + n_base + ci*16 + lr] = (f16)acc[mi][ci][r];
      }
    }
  }
}

// ---------------- MFMA GEMM, f16 A: C = A @ W^T, f16 out ----------------
template<int K>
__global__ __launch_bounds__(256) void gemm_f16_kernel(
    const f16* __restrict__ A, const f16* __restrict__ W,
    f16* __restrict__ C, int M, int N)
{
  const int lane = threadIdx.x & 63;
  const int wave = threadIdx.x >> 6;
  const int wm = wave >> 1, wc = wave & 1;
  const int m_base = blockIdx.x*128 + wm*64;
  const int n_base = blockIdx.y*128 + wc*64;
  const int lr = lane & 15;
  const int lk = (lane >> 4) * 8;
  f32x4 acc[4][4] = {};
  const f16* aptr[4]; const f16* bptr[4];
  #pragma unroll
  for (int mi = 0; mi < 4; ++mi){
    int r = m_base + mi*16 + lr; if (r >= M) r = M - 1;
    aptr[mi] = A + (size_t)r*K + lk;
  }
  #pragma unroll
  for (int ci = 0; ci < 4; ++ci){
    int c = n_base + ci*16 + lr;
    bptr[ci] = W + (size_t)c*K + lk;
  }
  #pragma unroll
  for (int k0 = 0; k0 < K; k0 += 32){
    f16x8 a[4], b[4];
    #pragma unroll
    for (int mi = 0; mi < 4; ++mi) a[mi] = *(const f16x8*)(aptr[mi] + k0);
    #pragma unroll
    for (int ci = 0; ci < 4; ++ci) b[ci] = *(const f16x8*)(bptr[ci] + k0);
    #pragma unroll
    for (int mi = 0; mi < 4; ++mi)
      #pragma unroll
      for (int ci = 0; ci < 4; ++ci)
        acc[mi][ci] = __builtin_amdgcn_mfma_f32_16x16x32_f16(a[mi], b[ci], acc[mi][ci], 0, 0, 0);
  }
  const int r0 = (lane >> 4)*4;
  #pragma unroll
  for (int mi = 0; mi < 4; ++mi){
    #pragma unroll
    for (int r = 0; r < 4; ++r){
      const int row = m_base + mi*16 + r0 + r;
      if (row < M){
        #pragma unroll
        for (int ci = 0; ci < 4; ++ci)
          C[(size_t)row*N + n_base + ci*16 + lr] = (f16)acc[mi][ci][r];
      }
    }
  }
}

// ---------------- fused GRU step (MFMA): gh = h @ Whh^T (3 gates) + gate combine ----------------
// Wave tile 32 rows x 32 cols x 3 gates; block 2x2 waves = 64x64. grid.y = H/64.
template<int H>
__global__ __launch_bounds__(256) void gru_mfma_kernel(
    const f16* __restrict__ h16, const float* __restrict__ h32,
    const f16* __restrict__ W16,            // (3H, H) row-major
    const f16* __restrict__ GI,             // (M, 3H) no bias
    const float* __restrict__ bih, const float* __restrict__ bhh,  // (3H)
    float* __restrict__ o32, f16* __restrict__ o16, int M)
{
  const int lane = threadIdx.x & 63;
  const int wave = threadIdx.x >> 6;
  const int wm = wave >> 1, wc = wave & 1;
  const int m_base = blockIdx.x*64 + wm*32;
  const int c_base = blockIdx.y*64 + wc*32;
  const int lr = lane & 15;
  const int lk = (lane >> 4)*8;
  f32x4 acc[2][2][3] = {};
  const f16* aptr[2]; const f16* bptr[2][3];
  #pragma unroll
  for (int mi = 0; mi < 2; ++mi){
    int r = m_base + mi*16 + lr; if (r >= M) r = M - 1;
    aptr[mi] = h16 + (size_t)r*H + lk;
  }
  #pragma unroll
  for (int ci = 0; ci < 2; ++ci)
    #pragma unroll
    for (int g = 0; g < 3; ++g){
      int c = g*H + c_base + ci*16 + lr;
      bptr[ci][g] = W16 + (size_t)c*H + lk;
    }
  #pragma unroll
  for (int k0 = 0; k0 < H; k0 += 32){
    f16x8 a[2], b[2][3];
    #pragma unroll
    for (int mi = 0; mi < 2; ++mi) a[mi] = *(const f16x8*)(aptr[mi] + k0);
    #pragma unroll
    for (int ci = 0; ci < 2; ++ci)
      #pragma unroll
      for (int g = 0; g < 3; ++g) b[ci][g] = *(const f16x8*)(bptr[ci][g] + k0);
    #pragma unroll
    for (int mi = 0; mi < 2; ++mi)
      #pragma unroll
      for (int ci = 0; ci < 2; ++ci)
        #pragma unroll
        for (int g = 0; g < 3; ++g)
          acc[mi][ci][g] = __builtin_amdgcn_mfma_f32_16x16x32_f16(a[mi], b[ci][g], acc[mi][ci][g], 0, 0, 0);
  }
  const int r0 = (lane >> 4)*4;
  #pragma unroll
  for (int mi = 0; mi < 2; ++mi){
    #pragma unroll
    for (int r = 0; r < 4; ++r){
      const int row = m_base + mi*16 + r0 + r;
      if (row >= M) continue;
      const f16* gi = GI + (size_t)row*3*H;
      #pragma unroll
      for (int ci = 0; ci < 2; ++ci){
        const int col = c_base + ci*16 + lr;
        const float gr = (float)gi[col]     + bih[col]     + acc[mi][ci][0][r] + bhh[col];
        const float gz = (float)gi[H+col]   + bih[H+col]   + acc[mi][ci][1][r] + bhh[H+col];
        const float rg = sigmoidf_(gr);
        const float zg = sigmoidf_(gz);
        const float ng = tanhf((float)gi[2*H+col] + bih[2*H+col] + rg*(acc[mi][ci][2][r] + bhh[2*H+col]));
        const float hp = h32[(size_t)row*H + col];
        const float hv = (1.0f - zg)*ng + zg*hp;
        o32[(size_t)row*H + col] = hv;
        o16[(size_t)row*H + col] = (f16)hv;
      }
    }
  }
}

// ---------------- batched graph conv over all t (f16 gather, fp32 accumulate) ----------------
// H=256, 128 threads/node, relu, f16 out. grid = (NN, TT); x-major keeps same-t blocks co-resident.
__global__ __launch_bounds__(128) void conv1_kernel(
    const f16* __restrict__ hall, const int* __restrict__ perm,
    const float* __restrict__ ew, const int* __restrict__ off,
    const float* __restrict__ dis, const float* __restrict__ bias,
    f16* __restrict__ outall)
{
  const int i = blockIdx.x;
  const int t = blockIdx.y;
  const int f = threadIdx.x;            // 0..127 (half2 index)
  const f16x2* hp = (const f16x2*)(hall + (size_t)t*NN*H1C);
  const float d = dis[i];
  const f16x2 sv = hp[(size_t)i*128 + f];
  float a0 = d*d*(float)sv[0];
  float a1 = d*d*(float)sv[1];
  int e = off[i]; const int e2 = off[i+1];
  for (; e + 4 <= e2; e += 4){
    const int   r0 = perm[e],   r1 = perm[e+1], r2 = perm[e+2], r3 = perm[e+3];
    const float w0 = ew[e],     w1 = ew[e+1],   w2 = ew[e+2],   w3 = ew[e+3];
    const f16x2 v0 = hp[(size_t)r0*128 + f];
    const f16x2 v1 = hp[(size_t)r1*128 + f];
    const f16x2 v2 = hp[(size_t)r2*128 + f];
    const f16x2 v3 = hp[(size_t)r3*128 + f];
    a0 += w0*(float)v0[0] + w1*(float)v1[0] + w2*(float)v2[0] + w3*(float)v3[0];
    a1 += w0*(float)v0[1] + w1*(float)v1[1] + w2*(float)v2[1] + w3*(float)v3[1];
  }
  for (; e < e2; ++e){
    const int r = perm[e]; const float w = ew[e];
    const f16x2 v = hp[(size_t)r*128 + f];
    a0 += w*(float)v[0]; a1 += w*(float)v[1];
  }
  const float2 bb = ((const float2*)bias)[f];
  a0 = fmaxf(a0 + bb.x, 0.0f);
  a1 = fmaxf(a1 + bb.y, 0.0f);
  f16x2 o; o[0] = (f16)a0; o[1] = (f16)a1;
  ((f16x2*)(outall + (size_t)t*NN*H1C))[(size_t)i*128 + f] = o;
}

// conv2: H=128, single t, 64 threads/node, no relu, fp32 out
__global__ __launch_bounds__(64) void conv2_kernel(
    const f16* __restrict__ h, const int* __restrict__ perm,
    const float* __restrict__ ew, const int* __restrict__ off,
    const float* __restrict__ dis, const float* __restrict__ bias,
    float* __restrict__ out)
{
  const int i = blockIdx.x;
  const int f = threadIdx.x;            // 0..63 (half2 index)
  const f16x2* hp = (const f16x2*)h;
  const float d = dis[i];
  const f16x2 sv = hp[(size_t)i*64 + f];
  float a0 = d*d*(float)sv[0];
  float a1 = d*d*(float)sv[1];
  int e = off[i]; const int e2 = off[i+1];
  for (; e + 4 <= e2; e += 4){
    const int   r0 = perm[e],   r1 = perm[e+1], r2 = perm[e+2], r3 = perm[e+3];
    const float w0 = ew[e],     w1 = ew[e+1],   w2 = ew[e+2],   w3 = ew[e+3];
    const f16x2 v0 = hp[(size_t)r0*64 + f];
    const f16x2 v1 = hp[(size_t)r1*64 + f];
    const f16x2 v2 = hp[(size_t)r2*64 + f];
    const f16x2 v3 = hp[(size_t)r3*64 + f];
    a0 += w0*(float)v0[0] + w1*(float)v1[0] + w2*(float)v2[0] + w3*(float)v3[0];
    a1 += w0*(float)v0[1] + w1*(float)v1[1] + w2*(float)v2[1] + w3*(float)v3[1];
  }
  for (; e < e2; ++e){
    const int r = perm[e]; const float w = ew[e];
    const f16x2 v = hp[(size_t)r*64 + f];
    a0 += w*(float)v[0]; a1 += w*(float)v[1];
  }
  const float2 bb = ((const float2*)bias)[f];
  ((float2*)out)[(size_t)i*64 + f] = make_float2(a0 + bb.x, a1 + bb.y);
}

// ---------------- final dense + softmax ----------------
__global__ __launch_bounds__(256) void dense_kernel(const float* __restrict__ flat,
    const float* __restrict__ linW, float* __restrict__ logits)
{
  const int j   = blockIdx.x;
  const int tid = threadIdx.x;
  const int Q4  = FLATSZ/4;                  // 320000
  const int CH4 = Q4/16;                     // 20000 (gridDim.y == 16)
  const int s4  = blockIdx.y*CH4;
  const int e4  = s4 + CH4;
  const float4* w4 = (const float4*)&linW[(size_t)j*FLATSZ];
  const float4* f4 = (const float4*)flat;
  float part = 0.0f;
  for (int i = s4 + tid; i < e4; i += 256){
    const float4 a = w4[i];
    const float4 b = f4[i];
    part += a.x*b.x + a.y*b.y + a.z*b.z + a.w*b.w;
  }
  __shared__ float red[256];
  red[tid] = part; __syncthreads();
  for (int s = 128; s > 0; s >>= 1){
    if (tid < s) red[tid] += red[tid + s];
    __syncthreads();
  }
  if (tid == 0) atomicAdd(&logits[j], red[0]);
}

__global__ __launch_bounds__(128) void softmax_kernel(const float* __restrict__ logits,
    const float* __restrict__ linb, float* __restrict__ out)
{
  __shared__ float red[128];
  const int tid = threadIdx.x;
  const float v = (tid < OUTD) ? logits[tid] + linb[tid] : -INFINITY;
  red[tid] = v; __syncthreads();
  for (int s = 64; s > 0; s >>= 1){
    if (tid < s) red[tid] = fmaxf(red[tid], red[tid + s]);
    __syncthreads();
  }
  const float mx = red[0]; __syncthreads();
  const float e = (tid < OUTD) ? expf(v - mx) : 0.0f;
  red[tid] = e; __syncthreads();
  for (int s = 64; s > 0; s >>= 1){
    if (tid < s) red[tid] += red[tid + s];
    __syncthreads();
  }
  const float inv = 1.0f/red[0];
  if (tid < OUTD) out[tid] = e*inv;
}

// ---------------- launch ----------------

extern "C" void kernel_launch(void* const* d_in, const int* in_sizes, int n_in,
                              void* d_out, int out_size, void* d_ws, size_t ws_size,
                              hipStream_t stream)
{
  const float* x     = (const float*)d_in[0];
  const int*   ei    = (const int*)  d_in[1];
  const float* W_ih1 = (const float*)d_in[2];
  const float* W_hh1 = (const float*)d_in[3];
  const float* b_ih1 = (const float*)d_in[4];
  const float* b_hh1 = (const float*)d_in[5];
  const float* bias1 = (const float*)d_in[6];
  const float* W_ih2 = (const float*)d_in[7];
  const float* W_hh2 = (const float*)d_in[8];
  const float* b_ih2 = (const float*)d_in[9];
  const float* b_hh2 = (const float*)d_in[10];
  const float* bias2 = (const float*)d_in[11];
  const float* lin_W = (const float*)d_in[12];
  const float* lin_b = (const float*)d_in[13];
  float* out = (float*)d_out;
  const int E = in_sizes[1]/2;
  (void)n_in; (void)out_size; (void)ws_size;

  char* p = (char*)d_ws;
  auto alloc = [&](size_t bytes)->void* {
    void* r = (void*)p;
    p += (bytes + 255) & ~(size_t)255;
    return r;
  };
  int*   cnt    = (int*)  alloc((size_t)NN*4);
  int*   cursor = (int*)  alloc((size_t)NN*4);
  int*   offs   = (int*)  alloc((size_t)(NN+1)*4);
  float* dis    = (float*)alloc((size_t)NN*4);
  int*   perm   = (int*)  alloc((size_t)E*4);
  float* ew     = (float*)alloc((size_t)E*4);
  f16*   gi1    = (f16*)  alloc((size_t)TT*NN*(3*H1C)*2);   // 369 MB; later aliased:
  f16*   x2all  = gi1;                                      //   123 MB (TT*NN*H1C)
  f16*   gi2all = gi1 + (size_t)TT*NN*H1C;                  //   184 MB (TT*NN*3*H2C)
  f16*   h1all  = (f16*)  alloc((size_t)TT*NN*H1C*2);       // 123 MB
  f16*   zbuf   = (f16*)  alloc((size_t)NN*H1C*2);
  float* h1f32a = (float*)alloc((size_t)NN*H1C*4);
  float* h1f32b = (float*)alloc((size_t)NN*H1C*4);
  float* h2f32a = (float*)alloc((size_t)NN*H2C*4);
  float* h2f32b = (float*)alloc((size_t)NN*H2C*4);
  f16*   h2f16a = (f16*)  alloc((size_t)NN*H2C*2);
  f16*   h2f16b = (f16*)  alloc((size_t)NN*H2C*2);
  float* out2   = (float*)alloc((size_t)NN*H2C*4);
  f16*   wih1h  = (f16*)  alloc((size_t)3*H1C*DIN*2);
  f16*   whh1h  = (f16*)  alloc((size_t)3*H1C*H1C*2);
  f16*   wih2h  = (f16*)  alloc((size_t)3*H2C*H1C*2);
  f16*   whh2h  = (f16*)  alloc((size_t)3*H2C*H2C*2);
  float* logits = (float*)alloc((size_t)OUTD*4);

  // ---- graph preprocessing ----
  init_kernel   <<<(NN+255)/256, 256, 0, stream>>>(cnt, cursor, logits, NN);
  count_kernel  <<<(E+255)/256, 256, 0, stream>>>(ei, cnt, E);
  dis_kernel    <<<(NN+255)/256, 256, 0, stream>>>(cnt, dis, NN);
  scan_kernel   <<<1, 256, 0, stream>>>(cnt, offs, NN);
  scatter_kernel<<<(E+255)/256, 256, 0, stream>>>(ei, dis, offs, cursor, perm, ew, E);

  // ---- zero states ----
  zero16_kernel<<<((NN*H1C*4/16)+255)/256, 256, 0, stream>>>((uint4*)h1f32a, NN*H1C*4/16);
  zero16_kernel<<<((NN*H1C*2/16)+255)/256, 256, 0, stream>>>((uint4*)zbuf,   NN*H1C*2/16);
  zero16_kernel<<<((NN*H2C*4/16)+255)/256, 256, 0, stream>>>((uint4*)h2f32a, NN*H2C*4/16);
  zero16_kernel<<<((NN*H2C*2/16)+255)/256, 256, 0, stream>>>((uint4*)h2f16a, NN*H2C*2/16);

  // ---- f16 weight casts ----
  cast_f16_kernel<<<((3*H1C*DIN/4)+255)/256, 256, 0, stream>>>((const float4*)W_ih1, (f16x4*)wih1h, 3*H1C*DIN/4);
  cast_f16_kernel<<<((3*H1C*H1C/4)+255)/256, 256, 0, stream>>>((const float4*)W_hh1, (f16x4*)whh1h, 3*H1C*H1C/4);
  cast_f16_kernel<<<((3*H2C*H1C/4)+255)/256, 256, 0, stream>>>((const float4*)W_ih2, (f16x4*)wih2h, 3*H2C*H1C/4);
  cast_f16_kernel<<<((3*H2C*H2C/4)+255)/256, 256, 0, stream>>>((const float4*)W_hh2, (f16x4*)whh2h, 3*H2C*H2C/4);

  // ---- GI1 for all timesteps, fp32 x read directly: (TT*NN,128) x (768,128)^T ----
  gemm_f32a_kernel<DIN><<<dim3(TT*NN/128, (3*H1C)/128), 256, 0, stream>>>(x, wih1h, gi1, TT*NN, 3*H1C);

  // ---- layer-1 GRU chain; h1[t] stored for all t ----
  {
    float* h32c = h1f32a; float* h32n = h1f32b;
    for (int t = 0; t < TT; ++t){
      const f16* hprev = (t == 0) ? zbuf : (h1all + (size_t)(t-1)*NN*H1C);
      gru_mfma_kernel<H1C><<<dim3((NN+63)/64, H1C/64), 256, 0, stream>>>(
          hprev, h32c, whh1h, gi1 + (size_t)t*NN*(3*H1C), b_ih1, b_hh1,
          h32n, h1all + (size_t)t*NN*H1C, NN);
      float* tmp = h32c; h32c = h32n; h32n = tmp;
    }
  }

  // ---- batched conv1 over all t (aliases onto gi1 region; gi1 fully consumed) ----
  conv1_kernel<<<dim3(NN, TT), 128, 0, stream>>>(h1all, perm, ew, offs, dis, bias1, x2all);

  // ---- batched GI2: (TT*NN,256) x (384,256)^T ----
  gemm_f16_kernel<H1C><<<dim3(TT*NN/128, (3*H2C)/128), 256, 0, stream>>>(x2all, wih2h, gi2all, TT*NN, 3*H2C);

  // ---- layer-2 GRU chain ----
  {
    float* h32c = h2f32a; float* h32n = h2f32b;
    f16*   h16c = h2f16a; f16*   h16n = h2f16b;
    for (int t = 0; t < TT; ++t){
      gru_mfma_kernel<H2C><<<dim3((NN+63)/64, H2C/64), 256, 0, stream>>>(
          h16c, h32c, whh2h, gi2all + (size_t)t*NN*(3*H2C), b_ih2, b_hh2,
          h32n, h16n, NN);
      float* tf = h32c; h32c = h32n; h32n = tf;
      f16*   th = h16c; h16c = h16n; h16n = th;
    }
    conv2_kernel<<<NN, 64, 0, stream>>>(h16c, perm, ew, offs, dis, bias2, out2);
  }

  dense_kernel<<<dim3(OUTD, 16), 256, 0, stream>>>(out2, lin_W, logits);
  softmax_kernel<<<1, 128, 0, stream>>>(logits, lin_b, out);
}

// Round 5
// 2453.234 us; speedup vs baseline: 2.0861x; 1.0467x over previous
//
#include <hip/hip_runtime.h>
#include <math.h>

#define TT   24
#define NN   10000
#define DIN  128
#define H1C  256
#define H2C  128
#define OUTD 100
#define FLATSZ (NN*H2C)

typedef _Float16 f16;
typedef _Float16 f16x2 __attribute__((ext_vector_type(2)));
typedef _Float16 f16x4 __attribute__((ext_vector_type(4)));
typedef _Float16 f16x8 __attribute__((ext_vector_type(8)));
typedef float    f32x4 __attribute__((ext_vector_type(4)));

__device__ __forceinline__ float sigmoidf_(float x){ return 1.0f/(1.0f+expf(-x)); }

__device__ __forceinline__ f16x8 cvt8(const float* p){
  const float4 v0 = *(const float4*)p;
  const float4 v1 = *(const float4*)(p + 4);
  f16x8 t;
  t[0]=(f16)v0.x; t[1]=(f16)v0.y; t[2]=(f16)v0.z; t[3]=(f16)v0.w;
  t[4]=(f16)v1.x; t[5]=(f16)v1.y; t[6]=(f16)v1.z; t[7]=(f16)v1.w;
  return t;
}

// ---------------- small utility kernels ----------------

__global__ __launch_bounds__(256) void zero16_kernel(uint4* __restrict__ p, int n16){
  int i = blockIdx.x*256 + threadIdx.x;
  if (i < n16) p[i] = make_uint4(0u,0u,0u,0u);
}

__global__ __launch_bounds__(256) void cast_f16_kernel(const float4* __restrict__ in,
                                                       f16x4* __restrict__ out, int n4){
  int i = blockIdx.x*256 + threadIdx.x;
  if (i < n4){
    float4 v = in[i];
    f16x4 o; o[0]=(f16)v.x; o[1]=(f16)v.y; o[2]=(f16)v.z; o[3]=(f16)v.w;
    out[i] = o;
  }
}

__global__ __launch_bounds__(256) void init_kernel(int* __restrict__ cnt, int* __restrict__ cursor,
                                                   float* __restrict__ logits, int n){
  int i = blockIdx.x*256 + threadIdx.x;
  if (i < n){ cnt[i] = 0; cursor[i] = 0; }
  if (i < OUTD) logits[i] = 0.0f;
}

__global__ __launch_bounds__(256) void count_kernel(const int* __restrict__ ei, int* __restrict__ cnt, int E){
  int e = blockIdx.x*256 + threadIdx.x;
  if (e < E) atomicAdd(&cnt[ei[E + e]], 1);
}

__global__ __launch_bounds__(256) void dis_kernel(const int* __restrict__ cnt, float* __restrict__ dis, int n){
  int i = blockIdx.x*256 + threadIdx.x;
  if (i < n) dis[i] = rsqrtf((float)(cnt[i] + 1));   // +1 self-loop
}

__global__ __launch_bounds__(256) void scan_kernel(const int* __restrict__ cnt, int* __restrict__ off, int n){
  __shared__ int sums[256];
  const int tid = threadIdx.x;
  const int CH  = 40;                  // 256*40 = 10240 >= NN
  const int base = tid*CH;
  int s = 0;
  for (int i = 0; i < CH; ++i){ int idx = base + i; if (idx < n) s += cnt[idx]; }
  sums[tid] = s; __syncthreads();
  for (int d = 1; d < 256; d <<= 1){
    int v = (tid >= d) ? sums[tid - d] : 0;
    __syncthreads();
    sums[tid] += v;
    __syncthreads();
  }
  int run = (tid == 0) ? 0 : sums[tid - 1];
  for (int i = 0; i < CH; ++i){
    int idx = base + i;
    if (idx < n){ off[idx] = run; run += cnt[idx]; }
  }
  if (tid == 0) off[n] = sums[255];
}

__global__ __launch_bounds__(256) void scatter_kernel(const int* __restrict__ ei, const float* __restrict__ dis,
                                                      const int* __restrict__ off, int* __restrict__ cursor,
                                                      int* __restrict__ perm, float* __restrict__ ew, int E){
  int e = blockIdx.x*256 + threadIdx.x;
  if (e < E){
    int r = ei[e];
    int c = ei[E + e];
    int pos = off[c] + atomicAdd(&cursor[c], 1);
    perm[pos] = r;
    ew[pos]   = dis[r]*dis[c];
  }
}

// ---------------- fused GRU step, layer 1 (per-t launch) ----------------
// acc = x[t]@Wih^T (fp32 A cvt, K=128) + h[t-1]@Whh^T (fp32 state cvt, K=256).
// grid (157, 4): 64-row x 64-col tiles; 256 thr = 2x2 waves of 32x32.
__global__ __launch_bounds__(256) void gru1_step_kernel(
    const float* __restrict__ xt, const f16* __restrict__ Wih,
    const f16* __restrict__ Whh, const float* __restrict__ bih,
    const float* __restrict__ bhh, const float* __restrict__ hprev32,
    float* __restrict__ hnext32, f16* __restrict__ hout16)
{
  constexpr int H = H1C;
  const int lane = threadIdx.x & 63;
  const int wave = threadIdx.x >> 6;
  const int wm = wave >> 1, wc = wave & 1;
  const int m_base = blockIdx.x*64 + wm*32;
  const int c_base = blockIdx.y*64 + wc*32;
  const int lr = lane & 15;
  const int lk8 = (lane >> 4)*8;
  const int r0 = (lane >> 4)*4;

  int aoffx[2], aoffh[2];
  #pragma unroll
  for (int mi = 0; mi < 2; ++mi){
    int r = m_base + mi*16 + lr; if (r >= NN) r = NN-1;
    aoffx[mi] = r*DIN + lk8;
    aoffh[mi] = r*H   + lk8;
  }
  int bxo[2][3], bho[2][3], colv[2];
  #pragma unroll
  for (int ci = 0; ci < 2; ++ci){
    const int col = c_base + ci*16 + lr;
    colv[ci] = col;
    #pragma unroll
    for (int g = 0; g < 3; ++g){
      bxo[ci][g] = (g*H + col)*DIN + lk8;
      bho[ci][g] = (g*H + col)*H   + lk8;
    }
  }
  float bR[2], bZ[2], bNi[2], bNh[2];
  #pragma unroll
  for (int ci = 0; ci < 2; ++ci){
    bR[ci]  = bih[colv[ci]]     + bhh[colv[ci]];
    bZ[ci]  = bih[H+colv[ci]]   + bhh[H+colv[ci]];
    bNi[ci] = bih[2*H+colv[ci]];
    bNh[ci] = bhh[2*H+colv[ci]];
  }

  f32x4 acc[2][2][4] = {};   // 0=r, 1=z, 2=n_x, 3=n_h

  // x part, K = 128
  #pragma unroll
  for (int k0 = 0; k0 < DIN; k0 += 32){
    f16x8 a[2], b[2][3];
    #pragma unroll
    for (int mi = 0; mi < 2; ++mi) a[mi] = cvt8(xt + aoffx[mi] + k0);
    #pragma unroll
    for (int ci = 0; ci < 2; ++ci)
      #pragma unroll
      for (int g = 0; g < 3; ++g)
        b[ci][g] = *(const f16x8*)(Wih + bxo[ci][g] + k0);
    #pragma unroll
    for (int mi = 0; mi < 2; ++mi)
      #pragma unroll
      for (int ci = 0; ci < 2; ++ci){
        acc[mi][ci][0] = __builtin_amdgcn_mfma_f32_16x16x32_f16(a[mi], b[ci][0], acc[mi][ci][0], 0,0,0);
        acc[mi][ci][1] = __builtin_amdgcn_mfma_f32_16x16x32_f16(a[mi], b[ci][1], acc[mi][ci][1], 0,0,0);
        acc[mi][ci][2] = __builtin_amdgcn_mfma_f32_16x16x32_f16(a[mi], b[ci][2], acc[mi][ci][2], 0,0,0);
      }
  }
  // h part, K = 256 (fp32 state, in-register cvt)
  #pragma unroll
  for (int k0 = 0; k0 < H; k0 += 32){
    f16x8 a[2], b[2][3];
    #pragma unroll
    for (int mi = 0; mi < 2; ++mi) a[mi] = cvt8(hprev32 + aoffh[mi] + k0);
    #pragma unroll
    for (int ci = 0; ci < 2; ++ci)
      #pragma unroll
      for (int g = 0; g < 3; ++g)
        b[ci][g] = *(const f16x8*)(Whh + bho[ci][g] + k0);
    #pragma unroll
    for (int mi = 0; mi < 2; ++mi)
      #pragma unroll
      for (int ci = 0; ci < 2; ++ci){
        acc[mi][ci][0] = __builtin_amdgcn_mfma_f32_16x16x32_f16(a[mi], b[ci][0], acc[mi][ci][0], 0,0,0);
        acc[mi][ci][1] = __builtin_amdgcn_mfma_f32_16x16x32_f16(a[mi], b[ci][1], acc[mi][ci][1], 0,0,0);
        acc[mi][ci][3] = __builtin_amdgcn_mfma_f32_16x16x32_f16(a[mi], b[ci][2], acc[mi][ci][3], 0,0,0);
      }
  }
  // epilogue
  #pragma unroll
  for (int mi = 0; mi < 2; ++mi){
    #pragma unroll
    for (int r = 0; r < 4; ++r){
      const int row = m_base + mi*16 + r0 + r;
      if (row >= NN) continue;
      #pragma unroll
      for (int ci = 0; ci < 2; ++ci){
        const float rg = sigmoidf_(acc[mi][ci][0][r] + bR[ci]);
        const float zg = sigmoidf_(acc[mi][ci][1][r] + bZ[ci]);
        const float ng = tanhf(acc[mi][ci][2][r] + bNi[ci] + rg*(acc[mi][ci][3][r] + bNh[ci]));
        const float hp = hprev32[(size_t)row*H + colv[ci]];
        const float hv = (1.0f - zg)*ng + zg*hp;
        hnext32[(size_t)row*H + colv[ci]] = hv;
        hout16 [(size_t)row*H + colv[ci]] = (f16)hv;
      }
    }
  }
}

// ---------------- fused GRU step, layer 2 (per-t launch) ----------------
// acc = x2[t]@Wih2^T (f16 A, K=256) + h[t-1]@Whh2^T (fp32 state cvt, K=128). grid (157,2).
__global__ __launch_bounds__(256) void gru2_step_kernel(
    const f16* __restrict__ x2t, const f16* __restrict__ Wih,
    const f16* __restrict__ Whh, const float* __restrict__ bih,
    const float* __restrict__ bhh, const float* __restrict__ hprev32,
    float* __restrict__ hnext32)
{
  constexpr int H  = H2C;   // 128
  constexpr int KX = H1C;   // 256
  const int lane = threadIdx.x & 63;
  const int wave = threadIdx.x >> 6;
  const int wm = wave >> 1, wc = wave & 1;
  const int m_base = blockIdx.x*64 + wm*32;
  const int c_base = blockIdx.y*64 + wc*32;
  const int lr = lane & 15;
  const int lk8 = (lane >> 4)*8;
  const int r0 = (lane >> 4)*4;

  int aoffx[2], aoffh[2];
  #pragma unroll
  for (int mi = 0; mi < 2; ++mi){
    int r = m_base + mi*16 + lr; if (r >= NN) r = NN-1;
    aoffx[mi] = r*KX + lk8;
    aoffh[mi] = r*H  + lk8;
  }
  int bxo[2][3], bho[2][3], colv[2];
  #pragma unroll
  for (int ci = 0; ci < 2; ++ci){
    const int col = c_base + ci*16 + lr;
    colv[ci] = col;
    #pragma unroll
    for (int g = 0; g < 3; ++g){
      bxo[ci][g] = (g*H + col)*KX + lk8;
      bho[ci][g] = (g*H + col)*H  + lk8;
    }
  }
  float bR[2], bZ[2], bNi[2], bNh[2];
  #pragma unroll
  for (int ci = 0; ci < 2; ++ci){
    bR[ci]  = bih[colv[ci]]     + bhh[colv[ci]];
    bZ[ci]  = bih[H+colv[ci]]   + bhh[H+colv[ci]];
    bNi[ci] = bih[2*H+colv[ci]];
    bNh[ci] = bhh[2*H+colv[ci]];
  }

  f32x4 acc[2][2][4] = {};

  // x part, K = 256 (f16 A)
  #pragma unroll
  for (int k0 = 0; k0 < KX; k0 += 32){
    f16x8 a[2], b[2][3];
    #pragma unroll
    for (int mi = 0; mi < 2; ++mi) a[mi] = *(const f16x8*)(x2t + aoffx[mi] + k0);
    #pragma unroll
    for (int ci = 0; ci < 2; ++ci)
      #pragma unroll
      for (int g = 0; g < 3; ++g)
        b[ci][g] = *(const f16x8*)(Wih + bxo[ci][g] + k0);
    #pragma unroll
    for (int mi = 0; mi < 2; ++mi)
      #pragma unroll
      for (int ci = 0; ci < 2; ++ci){
        acc[mi][ci][0] = __builtin_amdgcn_mfma_f32_16x16x32_f16(a[mi], b[ci][0], acc[mi][ci][0], 0,0,0);
        acc[mi][ci][1] = __builtin_amdgcn_mfma_f32_16x16x32_f16(a[mi], b[ci][1], acc[mi][ci][1], 0,0,0);
        acc[mi][ci][2] = __builtin_amdgcn_mfma_f32_16x16x32_f16(a[mi], b[ci][2], acc[mi][ci][2], 0,0,0);
      }
  }
  // h part, K = 128 (fp32 state cvt)
  #pragma unroll
  for (int k0 = 0; k0 < H; k0 += 32){
    f16x8 a[2], b[2][3];
    #pragma unroll
    for (int mi = 0; mi < 2; ++mi) a[mi] = cvt8(hprev32 + aoffh[mi] + k0);
    #pragma unroll
    for (int ci = 0; ci < 2; ++ci)
      #pragma unroll
      for (int g = 0; g < 3; ++g)
        b[ci][g] = *(const f16x8*)(Whh + bho[ci][g] + k0);
    #pragma unroll
    for (int mi = 0; mi < 2; ++mi)
      #pragma unroll
      for (int ci = 0; ci < 2; ++ci){
        acc[mi][ci][0] = __builtin_amdgcn_mfma_f32_16x16x32_f16(a[mi], b[ci][0], acc[mi][ci][0], 0,0,0);
        acc[mi][ci][1] = __builtin_amdgcn_mfma_f32_16x16x32_f16(a[mi], b[ci][1], acc[mi][ci][1], 0,0,0);
        acc[mi][ci][3] = __builtin_amdgcn_mfma_f32_16x16x32_f16(a[mi], b[ci][2], acc[mi][ci][3], 0,0,0);
      }
  }
  #pragma unroll
  for (int mi = 0; mi < 2; ++mi){
    #pragma unroll
    for (int r = 0; r < 4; ++r){
      const int row = m_base + mi*16 + r0 + r;
      if (row >= NN) continue;
      #pragma unroll
      for (int ci = 0; ci < 2; ++ci){
        const float rg = sigmoidf_(acc[mi][ci][0][r] + bR[ci]);
        const float zg = sigmoidf_(acc[mi][ci][1][r] + bZ[ci]);
        const float ng = tanhf(acc[mi][ci][2][r] + bNi[ci] + rg*(acc[mi][ci][3][r] + bNh[ci]));
        const float hp = hprev32[(size_t)row*H + colv[ci]];
        hnext32[(size_t)row*H + colv[ci]] = (1.0f - zg)*ng + zg*hp;
      }
    }
  }
}

// ---------------- batched graph conv, XCD-pinned t mapping ----------------
// grid = TT*NN 1D. xcd = b&7 owns t in {xcd, xcd+8, xcd+16} (blocks round-robin across XCDs).
__global__ __launch_bounds__(128) void conv1_kernel(
    const f16* __restrict__ hall, const int* __restrict__ perm,
    const float* __restrict__ ew, const int* __restrict__ off,
    const float* __restrict__ dis, const float* __restrict__ bias,
    f16* __restrict__ outall)
{
  const int b   = blockIdx.x;
  const int xcd = b & 7;
  const int j   = b >> 3;          // 0 .. 3*NN-1
  const int tq  = j / NN;          // 0..2
  const int i   = j - tq*NN;
  const int t   = xcd + 8*tq;
  const int f   = threadIdx.x;     // 0..127 (half2 index)
  const f16x2* hp = (const f16x2*)(hall + (size_t)t*NN*H1C);
  const float d = dis[i];
  const f16x2 sv = hp[(size_t)i*128 + f];
  float a0 = d*d*(float)sv[0];
  float a1 = d*d*(float)sv[1];
  int e = off[i]; const int e2 = off[i+1];
  for (; e + 4 <= e2; e += 4){
    const int   r0 = perm[e],   r1 = perm[e+1], r2 = perm[e+2], r3 = perm[e+3];
    const float w0 = ew[e],     w1 = ew[e+1],   w2 = ew[e+2],   w3 = ew[e+3];
    const f16x2 v0 = hp[(size_t)r0*128 + f];
    const f16x2 v1 = hp[(size_t)r1*128 + f];
    const f16x2 v2 = hp[(size_t)r2*128 + f];
    const f16x2 v3 = hp[(size_t)r3*128 + f];
    a0 += w0*(float)v0[0] + w1*(float)v1[0] + w2*(float)v2[0] + w3*(float)v3[0];
    a1 += w0*(float)v0[1] + w1*(float)v1[1] + w2*(float)v2[1] + w3*(float)v3[1];
  }
  for (; e < e2; ++e){
    const int r = perm[e]; const float w = ew[e];
    const f16x2 v = hp[(size_t)r*128 + f];
    a0 += w*(float)v[0]; a1 += w*(float)v[1];
  }
  const float2 bb = ((const float2*)bias)[f];
  a0 = fmaxf(a0 + bb.x, 0.0f);
  a1 = fmaxf(a1 + bb.y, 0.0f);
  f16x2 o; o[0] = (f16)a0; o[1] = (f16)a1;
  ((f16x2*)(outall + (size_t)t*NN*H1C))[(size_t)i*128 + f] = o;
}

// conv2: H=128, single t, fp32 input (final h2 state), 64 threads/node, no relu, fp32 out
__global__ __launch_bounds__(64) void conv2_kernel(
    const float* __restrict__ h, const int* __restrict__ perm,
    const float* __restrict__ ew, const int* __restrict__ off,
    const float* __restrict__ dis, const float* __restrict__ bias,
    float* __restrict__ out)
{
  const int i = blockIdx.x;
  const int f = threadIdx.x;            // 0..63 (float2 index)
  const float2* hp = (const float2*)h;
  const float d = dis[i];
  const float2 sv = hp[(size_t)i*64 + f];
  float a0 = d*d*sv.x;
  float a1 = d*d*sv.y;
  int e = off[i]; const int e2 = off[i+1];
  for (; e + 4 <= e2; e += 4){
    const int   r0 = perm[e],   r1 = perm[e+1], r2 = perm[e+2], r3 = perm[e+3];
    const float w0 = ew[e],     w1 = ew[e+1],   w2 = ew[e+2],   w3 = ew[e+3];
    const float2 v0 = hp[(size_t)r0*64 + f];
    const float2 v1 = hp[(size_t)r1*64 + f];
    const float2 v2 = hp[(size_t)r2*64 + f];
    const float2 v3 = hp[(size_t)r3*64 + f];
    a0 += w0*v0.x + w1*v1.x + w2*v2.x + w3*v3.x;
    a1 += w0*v0.y + w1*v1.y + w2*v2.y + w3*v3.y;
  }
  for (; e < e2; ++e){
    const int r = perm[e]; const float w = ew[e];
    const float2 v = hp[(size_t)r*64 + f];
    a0 += w*v.x; a1 += w*v.y;
  }
  const float2 bb = ((const float2*)bias)[f];
  ((float2*)out)[(size_t)i*64 + f] = make_float2(a0 + bb.x, a1 + bb.y);
}

// ---------------- final dense + softmax ----------------
__global__ __launch_bounds__(256) void dense_kernel(const float* __restrict__ flat,
    const float* __restrict__ linW, float* __restrict__ logits)
{
  const int j   = blockIdx.x;
  const int tid = threadIdx.x;
  const int Q4  = FLATSZ/4;                  // 320000
  const int CH4 = Q4/16;                     // 20000 (gridDim.y == 16)
  const int s4  = blockIdx.y*CH4;
  const int e4  = s4 + CH4;
  const float4* w4 = (const float4*)&linW[(size_t)j*FLATSZ];
  const float4* f4 = (const float4*)flat;
  float part = 0.0f;
  for (int i = s4 + tid; i < e4; i += 256){
    const float4 a = w4[i];
    const float4 b = f4[i];
    part += a.x*b.x + a.y*b.y + a.z*b.z + a.w*b.w;
  }
  __shared__ float red[256];
  red[tid] = part; __syncthreads();
  for (int s = 128; s > 0; s >>= 1){
    if (tid < s) red[tid] += red[tid + s];
    __syncthreads();
  }
  if (tid == 0) atomicAdd(&logits[j], red[0]);
}

__global__ __launch_bounds__(128) void softmax_kernel(const float* __restrict__ logits,
    const float* __restrict__ linb, float* __restrict__ out)
{
  __shared__ float red[128];
  const int tid = threadIdx.x;
  const float v = (tid < OUTD) ? logits[tid] + linb[tid] : -INFINITY;
  red[tid] = v; __syncthreads();
  for (int s = 64; s > 0; s >>= 1){
    if (tid < s) red[tid] = fmaxf(red[tid], red[tid + s]);
    __syncthreads();
  }
  const float mx = red[0]; __syncthreads();
  const float e = (tid < OUTD) ? expf(v - mx) : 0.0f;
  red[tid] = e; __syncthreads();
  for (int s = 64; s > 0; s >>= 1){
    if (tid < s) red[tid] += red[tid + s];
    __syncthreads();
  }
  const float inv = 1.0f/red[0];
  if (tid < OUTD) out[tid] = e*inv;
}

// ---------------- launch ----------------

extern "C" void kernel_launch(void* const* d_in, const int* in_sizes, int n_in,
                              void* d_out, int out_size, void* d_ws, size_t ws_size,
                              hipStream_t stream)
{
  const float* x     = (const float*)d_in[0];
  const int*   ei    = (const int*)  d_in[1];
  const float* W_ih1 = (const float*)d_in[2];
  const float* W_hh1 = (const float*)d_in[3];
  const float* b_ih1 = (const float*)d_in[4];
  const float* b_hh1 = (const float*)d_in[5];
  const float* bias1 = (const float*)d_in[6];
  const float* W_ih2 = (const float*)d_in[7];
  const float* W_hh2 = (const float*)d_in[8];
  const float* b_ih2 = (const float*)d_in[9];
  const float* b_hh2 = (const float*)d_in[10];
  const float* bias2 = (const float*)d_in[11];
  const float* lin_W = (const float*)d_in[12];
  const float* lin_b = (const float*)d_in[13];
  float* out = (float*)d_out;
  const int E = in_sizes[1]/2;
  (void)n_in; (void)out_size; (void)ws_size;

  char* p = (char*)d_ws;
  auto alloc = [&](size_t bytes)->void* {
    void* r = (void*)p;
    p += (bytes + 255) & ~(size_t)255;
    return r;
  };
  int*   cnt    = (int*)  alloc((size_t)NN*4);
  int*   cursor = (int*)  alloc((size_t)NN*4);
  int*   offs   = (int*)  alloc((size_t)(NN+1)*4);
  float* dis    = (float*)alloc((size_t)NN*4);
  int*   perm   = (int*)  alloc((size_t)E*4);
  float* ew     = (float*)alloc((size_t)E*4);
  f16*   h1all  = (f16*)  alloc((size_t)TT*NN*H1C*2);   // 123 MB
  f16*   x2all  = (f16*)  alloc((size_t)TT*NN*H1C*2);   // 123 MB
  float* h1sa   = (float*)alloc((size_t)NN*H1C*4);      // zeroed (contiguous with h2sa)
  float* h2sa   = (float*)alloc((size_t)NN*H2C*4);      // zeroed
  float* h1sb   = (float*)alloc((size_t)NN*H1C*4);
  float* h2sb   = (float*)alloc((size_t)NN*H2C*4);
  float* out2   = (float*)alloc((size_t)NN*H2C*4);
  f16*   wih1h  = (f16*)  alloc((size_t)3*H1C*DIN*2);
  f16*   whh1h  = (f16*)  alloc((size_t)3*H1C*H1C*2);
  f16*   wih2h  = (f16*)  alloc((size_t)3*H2C*H1C*2);
  f16*   whh2h  = (f16*)  alloc((size_t)3*H2C*H2C*2);
  float* logits = (float*)alloc((size_t)OUTD*4);

  // ---- graph preprocessing ----
  init_kernel   <<<(NN+255)/256, 256, 0, stream>>>(cnt, cursor, logits, NN);
  count_kernel  <<<(E+255)/256, 256, 0, stream>>>(ei, cnt, E);
  dis_kernel    <<<(NN+255)/256, 256, 0, stream>>>(cnt, dis, NN);
  scan_kernel   <<<1, 256, 0, stream>>>(cnt, offs, NN);
  scatter_kernel<<<(E+255)/256, 256, 0, stream>>>(ei, dis, offs, cursor, perm, ew, E);

  // ---- zero h1sa + h2sa (contiguous) ----
  {
    const int n16 = (NN*H1C*4 + NN*H2C*4)/16;
    zero16_kernel<<<(n16+255)/256, 256, 0, stream>>>((uint4*)h1sa, n16);
  }

  // ---- f16 weight casts ----
  cast_f16_kernel<<<((3*H1C*DIN/4)+255)/256, 256, 0, stream>>>((const float4*)W_ih1, (f16x4*)wih1h, 3*H1C*DIN/4);
  cast_f16_kernel<<<((3*H1C*H1C/4)+255)/256, 256, 0, stream>>>((const float4*)W_hh1, (f16x4*)whh1h, 3*H1C*H1C/4);
  cast_f16_kernel<<<((3*H2C*H1C/4)+255)/256, 256, 0, stream>>>((const float4*)W_ih2, (f16x4*)wih2h, 3*H2C*H1C/4);
  cast_f16_kernel<<<((3*H2C*H2C/4)+255)/256, 256, 0, stream>>>((const float4*)W_hh2, (f16x4*)whh2h, 3*H2C*H2C/4);

  const int MB = (NN + 63)/64;   // 157

  // ---- layer-1 GRU chain (per-t fused kernels) ----
  {
    float* hc = h1sa; float* hn = h1sb;
    for (int t = 0; t < TT; ++t){
      gru1_step_kernel<<<dim3(MB, H1C/64), 256, 0, stream>>>(
          x + (size_t)t*NN*DIN, wih1h, whh1h, b_ih1, b_hh1,
          hc, hn, h1all + (size_t)t*NN*H1C);
      float* tmp = hc; hc = hn; hn = tmp;
    }
  }

  // ---- batched conv1 over all t (XCD-pinned) ----
  conv1_kernel<<<TT*NN, 128, 0, stream>>>(h1all, perm, ew, offs, dis, bias1, x2all);

  // ---- layer-2 GRU chain (per-t fused kernels) ----
  float* h2final;
  {
    float* hc = h2sa; float* hn = h2sb;
    for (int t = 0; t < TT; ++t){
      gru2_step_kernel<<<dim3(MB, H2C/64), 256, 0, stream>>>(
          x2all + (size_t)t*NN*H1C, wih2h, whh2h, b_ih2, b_hh2, hc, hn);
      float* tmp = hc; hc = hn; hn = tmp;
    }
    h2final = hc;   // after even number of swaps, hc holds t=23 output
  }

  conv2_kernel<<<NN, 64, 0, stream>>>(h2final, perm, ew, offs, dis, bias2, out2);
  dense_kernel<<<dim3(OUTD, 16), 256, 0, stream>>>(out2, lin_W, logits);
  softmax_kernel<<<1, 128, 0, stream>>>(logits, lin_b, out);
}

// Round 6
// 2448.562 us; speedup vs baseline: 2.0900x; 1.0019x over previous
//
#include <hip/hip_runtime.h>
#include <math.h>

#define TT   24
#define NN   10000
#define DIN  128
#define H1C  256
#define H2C  128
#define OUTD 100
#define FLATSZ (NN*H2C)

typedef _Float16 f16;
typedef _Float16 f16x2 __attribute__((ext_vector_type(2)));
typedef _Float16 f16x4 __attribute__((ext_vector_type(4)));
typedef _Float16 f16x8 __attribute__((ext_vector_type(8)));
typedef float    f32x4 __attribute__((ext_vector_type(4)));

__device__ __forceinline__ float sigmoidf_(float x){ return 1.0f/(1.0f+expf(-x)); }

__device__ __forceinline__ f16x8 cvt8(const float* p){
  const float4 v0 = *(const float4*)p;
  const float4 v1 = *(const float4*)(p + 4);
  f16x8 t;
  t[0]=(f16)v0.x; t[1]=(f16)v0.y; t[2]=(f16)v0.z; t[3]=(f16)v0.w;
  t[4]=(f16)v1.x; t[5]=(f16)v1.y; t[6]=(f16)v1.z; t[7]=(f16)v1.w;
  return t;
}

// ---------------- small utility kernels ----------------

__global__ __launch_bounds__(256) void cast_f16_kernel(const float4* __restrict__ in,
                                                       f16x4* __restrict__ out, int n4){
  int i = blockIdx.x*256 + threadIdx.x;
  if (i < n4){
    float4 v = in[i];
    f16x4 o; o[0]=(f16)v.x; o[1]=(f16)v.y; o[2]=(f16)v.z; o[3]=(f16)v.w;
    out[i] = o;
  }
}

__global__ __launch_bounds__(256) void init_kernel(int* __restrict__ cnt, int* __restrict__ cursor,
                                                   float* __restrict__ logits, int n){
  int i = blockIdx.x*256 + threadIdx.x;
  if (i < n){ cnt[i] = 0; cursor[i] = 0; }
  if (i < OUTD) logits[i] = 0.0f;
}

__global__ __launch_bounds__(256) void count_kernel(const int* __restrict__ ei, int* __restrict__ cnt, int E){
  int e = blockIdx.x*256 + threadIdx.x;
  if (e < E) atomicAdd(&cnt[ei[E + e]], 1);
}

__global__ __launch_bounds__(256) void dis_kernel(const int* __restrict__ cnt, float* __restrict__ dis, int n){
  int i = blockIdx.x*256 + threadIdx.x;
  if (i < n) dis[i] = rsqrtf((float)(cnt[i] + 1));   // +1 self-loop
}

__global__ __launch_bounds__(256) void scan_kernel(const int* __restrict__ cnt, int* __restrict__ off, int n){
  __shared__ int sums[256];
  const int tid = threadIdx.x;
  const int CH  = 40;                  // 256*40 = 10240 >= NN
  const int base = tid*CH;
  int s = 0;
  for (int i = 0; i < CH; ++i){ int idx = base + i; if (idx < n) s += cnt[idx]; }
  sums[tid] = s; __syncthreads();
  for (int d = 1; d < 256; d <<= 1){
    int v = (tid >= d) ? sums[tid - d] : 0;
    __syncthreads();
    sums[tid] += v;
    __syncthreads();
  }
  int run = (tid == 0) ? 0 : sums[tid - 1];
  for (int i = 0; i < CH; ++i){
    int idx = base + i;
    if (idx < n){ off[idx] = run; run += cnt[idx]; }
  }
  if (tid == 0) off[n] = sums[255];
}

__global__ __launch_bounds__(256) void scatter_kernel(const int* __restrict__ ei, const float* __restrict__ dis,
                                                      const int* __restrict__ off, int* __restrict__ cursor,
                                                      int* __restrict__ perm, float* __restrict__ ew, int E){
  int e = blockIdx.x*256 + threadIdx.x;
  if (e < E){
    int r = ei[e];
    int c = ei[E + e];
    int pos = off[c] + atomicAdd(&cursor[c], 1);
    perm[pos] = r;
    ew[pos]   = dis[r]*dis[c];
  }
}

// ---------------- layer-1 GRU chain: ONE kernel, t-loop inside ----------------
// Each block owns 64 rows for all 24 steps (recurrence is row-local).
// h state: f16 in LDS (double-buffered, padded pitch) for MFMA A; fp32 in regs for z*h.
// 512 thr = 8 waves (2 row-groups x 4 col-groups of 32x32); ct loop covers 256 cols.
__global__ __launch_bounds__(512, 2) void gru1_chain_kernel(
    const float* __restrict__ x, const f16* __restrict__ Wih,
    const f16* __restrict__ Whh, const float* __restrict__ bih,
    const float* __restrict__ bhh, f16* __restrict__ h1all)
{
  constexpr int H = H1C;            // 256
  constexpr int PITCH = H + 8;      // 264 f16 = 528 B: 16B-aligned, 2-way bank alias (free)
  extern __shared__ char smem_raw[];
  f16* buf0 = (f16*)smem_raw;
  f16* buf1 = buf0 + 64*PITCH;

  const int tid  = threadIdx.x;
  const int lane = tid & 63;
  const int w    = tid >> 6;        // 0..7
  const int wm   = w >> 2;          // 0..1 row group
  const int wc   = w & 3;           // 0..3 col group
  const int lr   = lane & 15;
  const int lk8  = (lane >> 4) * 8;
  const int r0   = (lane >> 4) * 4;
  const int rowg_base = blockIdx.x*64;

  // zero buf0 (initial state)
  {
    unsigned int* z = (unsigned int*)buf0;
    for (int k = tid; k < 64*PITCH/2; k += 512) z[k] = 0u;
  }

  int aoffx[2]; int lrow[2];
  #pragma unroll
  for (int mi = 0; mi < 2; ++mi){
    lrow[mi] = wm*32 + mi*16 + lr;
    int rg = rowg_base + lrow[mi]; if (rg >= NN) rg = NN-1;
    aoffx[mi] = rg*DIN + lk8;
  }
  int colv[2][2];
  float bR[2][2], bZ[2][2], bNi[2][2], bNh[2][2];
  #pragma unroll
  for (int ct = 0; ct < 2; ++ct)
    #pragma unroll
    for (int ci = 0; ci < 2; ++ci){
      const int col = ct*128 + wc*32 + ci*16 + lr;
      colv[ct][ci] = col;
      bR[ct][ci]  = bih[col]       + bhh[col];
      bZ[ct][ci]  = bih[H+col]     + bhh[H+col];
      bNi[ct][ci] = bih[2*H+col];
      bNh[ct][ci] = bhh[2*H+col];
    }

  float hst[2][2][4][2] = {};   // [ct][mi][r][ci] fp32 state, thread-owned across t

  __syncthreads();

  for (int t = 0; t < TT; ++t){
    const float* xt = x + (size_t)t*NN*DIN;
    f16* cur = (t & 1) ? buf1 : buf0;
    f16* nxt = (t & 1) ? buf0 : buf1;
    f16* ho  = h1all + (size_t)t*NN*H;

    #pragma unroll
    for (int ct = 0; ct < 2; ++ct){
      int bxoc[2][3], bhoc[2][3];
      #pragma unroll
      for (int ci = 0; ci < 2; ++ci)
        #pragma unroll
        for (int g = 0; g < 3; ++g){
          const int col = colv[ct][ci];
          bxoc[ci][g] = (g*H + col)*DIN + lk8;
          bhoc[ci][g] = (g*H + col)*H   + lk8;
        }
      f32x4 acc[2][2][4] = {};   // 0=r, 1=z, 2=n_x, 3=n_h

      // x part, K = 128 (fp32 global, in-reg cvt)
      #pragma unroll
      for (int k0 = 0; k0 < DIN; k0 += 32){
        f16x8 a[2], b[2][3];
        #pragma unroll
        for (int mi = 0; mi < 2; ++mi) a[mi] = cvt8(xt + aoffx[mi] + k0);
        #pragma unroll
        for (int ci = 0; ci < 2; ++ci)
          #pragma unroll
          for (int g = 0; g < 3; ++g) b[ci][g] = *(const f16x8*)(Wih + bxoc[ci][g] + k0);
        #pragma unroll
        for (int mi = 0; mi < 2; ++mi)
          #pragma unroll
          for (int ci = 0; ci < 2; ++ci){
            acc[mi][ci][0] = __builtin_amdgcn_mfma_f32_16x16x32_f16(a[mi], b[ci][0], acc[mi][ci][0], 0,0,0);
            acc[mi][ci][1] = __builtin_amdgcn_mfma_f32_16x16x32_f16(a[mi], b[ci][1], acc[mi][ci][1], 0,0,0);
            acc[mi][ci][2] = __builtin_amdgcn_mfma_f32_16x16x32_f16(a[mi], b[ci][2], acc[mi][ci][2], 0,0,0);
          }
      }
      // h part, K = 256 (f16 from LDS)
      #pragma unroll
      for (int k0 = 0; k0 < H; k0 += 32){
        f16x8 a[2], b[2][3];
        #pragma unroll
        for (int mi = 0; mi < 2; ++mi) a[mi] = *(const f16x8*)&cur[lrow[mi]*PITCH + k0 + lk8];
        #pragma unroll
        for (int ci = 0; ci < 2; ++ci)
          #pragma unroll
          for (int g = 0; g < 3; ++g) b[ci][g] = *(const f16x8*)(Whh + bhoc[ci][g] + k0);
        #pragma unroll
        for (int mi = 0; mi < 2; ++mi)
          #pragma unroll
          for (int ci = 0; ci < 2; ++ci){
            acc[mi][ci][0] = __builtin_amdgcn_mfma_f32_16x16x32_f16(a[mi], b[ci][0], acc[mi][ci][0], 0,0,0);
            acc[mi][ci][1] = __builtin_amdgcn_mfma_f32_16x16x32_f16(a[mi], b[ci][1], acc[mi][ci][1], 0,0,0);
            acc[mi][ci][3] = __builtin_amdgcn_mfma_f32_16x16x32_f16(a[mi], b[ci][2], acc[mi][ci][3], 0,0,0);
          }
      }
      // epilogue: gates, state update, LDS next buffer + global f16
      #pragma unroll
      for (int mi = 0; mi < 2; ++mi){
        #pragma unroll
        for (int rr = 0; rr < 4; ++rr){
          const int lrw = wm*32 + mi*16 + r0 + rr;
          const int rg2 = rowg_base + lrw;
          #pragma unroll
          for (int ci = 0; ci < 2; ++ci){
            const int col = colv[ct][ci];
            const float rg_ = sigmoidf_(acc[mi][ci][0][rr] + bR[ct][ci]);
            const float zg  = sigmoidf_(acc[mi][ci][1][rr] + bZ[ct][ci]);
            const float ng  = tanhf(acc[mi][ci][2][rr] + bNi[ct][ci] + rg_*(acc[mi][ci][3][rr] + bNh[ct][ci]));
            const float hv  = (1.0f - zg)*ng + zg*hst[ct][mi][rr][ci];
            hst[ct][mi][rr][ci] = hv;
            nxt[lrw*PITCH + col] = (f16)hv;
            if (rg2 < NN) ho[(size_t)rg2*H + col] = (f16)hv;
          }
        }
      }
    }
    __syncthreads();
  }
}

// ---------------- layer-2 GRU chain: ONE kernel ----------------
// H=128 (single ct), x2 K=256 f16 global, h K=128 LDS. Writes only final fp32 state.
__global__ __launch_bounds__(512, 2) void gru2_chain_kernel(
    const f16* __restrict__ x2all, const f16* __restrict__ Wih,
    const f16* __restrict__ Whh, const float* __restrict__ bih,
    const float* __restrict__ bhh, float* __restrict__ h2fin)
{
  constexpr int H = H2C;            // 128
  constexpr int KX = H1C;           // 256
  constexpr int PITCH = H + 8;      // 136 f16 = 272 B: 16B-aligned, 2-way alias
  extern __shared__ char smem_raw[];
  f16* buf0 = (f16*)smem_raw;
  f16* buf1 = buf0 + 64*PITCH;

  const int tid  = threadIdx.x;
  const int lane = tid & 63;
  const int w    = tid >> 6;
  const int wm   = w >> 2;          // 0..1
  const int wc   = w & 3;           // 0..3
  const int lr   = lane & 15;
  const int lk8  = (lane >> 4) * 8;
  const int r0   = (lane >> 4) * 4;
  const int rowg_base = blockIdx.x*64;

  {
    unsigned int* z = (unsigned int*)buf0;
    for (int k = tid; k < 64*PITCH/2; k += 512) z[k] = 0u;
  }

  int aoffx[2]; int lrow[2];
  #pragma unroll
  for (int mi = 0; mi < 2; ++mi){
    lrow[mi] = wm*32 + mi*16 + lr;
    int rg = rowg_base + lrow[mi]; if (rg >= NN) rg = NN-1;
    aoffx[mi] = rg*KX + lk8;
  }
  int colv[2], bxoc[2][3], bhoc[2][3];
  float bR[2], bZ[2], bNi[2], bNh[2];
  #pragma unroll
  for (int ci = 0; ci < 2; ++ci){
    const int col = wc*32 + ci*16 + lr;
    colv[ci] = col;
    #pragma unroll
    for (int g = 0; g < 3; ++g){
      bxoc[ci][g] = (g*H + col)*KX + lk8;
      bhoc[ci][g] = (g*H + col)*H  + lk8;
    }
    bR[ci]  = bih[col]       + bhh[col];
    bZ[ci]  = bih[H+col]     + bhh[H+col];
    bNi[ci] = bih[2*H+col];
    bNh[ci] = bhh[2*H+col];
  }

  float hst[2][4][2] = {};

  __syncthreads();

  for (int t = 0; t < TT; ++t){
    const f16* xt = x2all + (size_t)t*NN*KX;
    f16* cur = (t & 1) ? buf1 : buf0;
    f16* nxt = (t & 1) ? buf0 : buf1;

    f32x4 acc[2][2][4] = {};

    // x part, K = 256 (f16 global)
    #pragma unroll
    for (int k0 = 0; k0 < KX; k0 += 32){
      f16x8 a[2], b[2][3];
      #pragma unroll
      for (int mi = 0; mi < 2; ++mi) a[mi] = *(const f16x8*)(xt + aoffx[mi] + k0);
      #pragma unroll
      for (int ci = 0; ci < 2; ++ci)
        #pragma unroll
        for (int g = 0; g < 3; ++g) b[ci][g] = *(const f16x8*)(Wih + bxoc[ci][g] + k0);
      #pragma unroll
      for (int mi = 0; mi < 2; ++mi)
        #pragma unroll
        for (int ci = 0; ci < 2; ++ci){
          acc[mi][ci][0] = __builtin_amdgcn_mfma_f32_16x16x32_f16(a[mi], b[ci][0], acc[mi][ci][0], 0,0,0);
          acc[mi][ci][1] = __builtin_amdgcn_mfma_f32_16x16x32_f16(a[mi], b[ci][1], acc[mi][ci][1], 0,0,0);
          acc[mi][ci][2] = __builtin_amdgcn_mfma_f32_16x16x32_f16(a[mi], b[ci][2], acc[mi][ci][2], 0,0,0);
        }
    }
    // h part, K = 128 (LDS)
    #pragma unroll
    for (int k0 = 0; k0 < H; k0 += 32){
      f16x8 a[2], b[2][3];
      #pragma unroll
      for (int mi = 0; mi < 2; ++mi) a[mi] = *(const f16x8*)&cur[lrow[mi]*PITCH + k0 + lk8];
      #pragma unroll
      for (int ci = 0; ci < 2; ++ci)
        #pragma unroll
        for (int g = 0; g < 3; ++g) b[ci][g] = *(const f16x8*)(Whh + bhoc[ci][g] + k0);
      #pragma unroll
      for (int mi = 0; mi < 2; ++mi)
        #pragma unroll
        for (int ci = 0; ci < 2; ++ci){
          acc[mi][ci][0] = __builtin_amdgcn_mfma_f32_16x16x32_f16(a[mi], b[ci][0], acc[mi][ci][0], 0,0,0);
          acc[mi][ci][1] = __builtin_amdgcn_mfma_f32_16x16x32_f16(a[mi], b[ci][1], acc[mi][ci][1], 0,0,0);
          acc[mi][ci][3] = __builtin_amdgcn_mfma_f32_16x16x32_f16(a[mi], b[ci][2], acc[mi][ci][3], 0,0,0);
        }
    }
    #pragma unroll
    for (int mi = 0; mi < 2; ++mi){
      #pragma unroll
      for (int rr = 0; rr < 4; ++rr){
        const int lrw = wm*32 + mi*16 + r0 + rr;
        const int rg2 = rowg_base + lrw;
        #pragma unroll
        for (int ci = 0; ci < 2; ++ci){
          const int col = colv[ci];
          const float rg_ = sigmoidf_(acc[mi][ci][0][rr] + bR[ci]);
          const float zg  = sigmoidf_(acc[mi][ci][1][rr] + bZ[ci]);
          const float ng  = tanhf(acc[mi][ci][2][rr] + bNi[ci] + rg_*(acc[mi][ci][3][rr] + bNh[ci]));
          const float hv  = (1.0f - zg)*ng + zg*hst[mi][rr][ci];
          hst[mi][rr][ci] = hv;
          nxt[lrw*PITCH + col] = (f16)hv;
          if (t == TT-1 && rg2 < NN) h2fin[(size_t)rg2*H + col] = hv;
        }
      }
    }
    __syncthreads();
  }
}

// ---------------- batched graph conv, (t,half)-sliced + XCD-pinned ----------------
// 48 slices of 2.56 MB (fit 4 MB per-XCD L2). xcd = b&7; 6 slices per XCD.
__global__ __launch_bounds__(64) void conv1_kernel(
    const f16* __restrict__ hall, const int* __restrict__ perm,
    const float* __restrict__ ew, const int* __restrict__ off,
    const float* __restrict__ dis, const float* __restrict__ bias,
    f16* __restrict__ outall)
{
  const int b    = blockIdx.x;
  const int xcd  = b & 7;
  const int j    = b >> 3;            // 0 .. 6*NN-1
  const int sq   = j / NN;            // 0..5
  const int i    = j - sq*NN;
  const int t    = xcd + 8*(sq >> 1); // {xcd, xcd+8, xcd+16}
  const int half = sq & 1;
  const int f    = threadIdx.x;       // 0..63 (f16x2 index within half)
  const f16x2* hp = (const f16x2*)(hall + (size_t)t*NN*H1C) + half*64;
  const float d = dis[i];
  const f16x2 sv = hp[(size_t)i*128 + f];
  float a0 = d*d*(float)sv[0];
  float a1 = d*d*(float)sv[1];
  int e = off[i]; const int e2 = off[i+1];
  for (; e + 8 <= e2; e += 8){
    int rr[8]; float ww[8];
    #pragma unroll
    for (int q = 0; q < 8; ++q){ rr[q] = perm[e+q]; ww[q] = ew[e+q]; }
    #pragma unroll
    for (int q = 0; q < 8; ++q){
      const f16x2 v = hp[(size_t)rr[q]*128 + f];
      a0 += ww[q]*(float)v[0];
      a1 += ww[q]*(float)v[1];
    }
  }
  for (; e < e2; ++e){
    const int r = perm[e]; const float wgt = ew[e];
    const f16x2 v = hp[(size_t)r*128 + f];
    a0 += wgt*(float)v[0]; a1 += wgt*(float)v[1];
  }
  const float2 bb = ((const float2*)bias)[half*64 + f];
  a0 = fmaxf(a0 + bb.x, 0.0f);
  a1 = fmaxf(a1 + bb.y, 0.0f);
  f16x2 o; o[0] = (f16)a0; o[1] = (f16)a1;
  ((f16x2*)(outall + (size_t)t*NN*H1C))[(size_t)i*128 + half*64 + f] = o;
}

// conv2: H=128, single t, fp32 input (final h2 state), no relu, fp32 out
__global__ __launch_bounds__(64) void conv2_kernel(
    const float* __restrict__ h, const int* __restrict__ perm,
    const float* __restrict__ ew, const int* __restrict__ off,
    const float* __restrict__ dis, const float* __restrict__ bias,
    float* __restrict__ out)
{
  const int i = blockIdx.x;
  const int f = threadIdx.x;            // 0..63 (float2 index)
  const float2* hp = (const float2*)h;
  const float d = dis[i];
  const float2 sv = hp[(size_t)i*64 + f];
  float a0 = d*d*sv.x;
  float a1 = d*d*sv.y;
  int e = off[i]; const int e2 = off[i+1];
  for (; e + 4 <= e2; e += 4){
    const int   r0 = perm[e],   r1 = perm[e+1], r2 = perm[e+2], r3 = perm[e+3];
    const float w0 = ew[e],     w1 = ew[e+1],   w2 = ew[e+2],   w3 = ew[e+3];
    const float2 v0 = hp[(size_t)r0*64 + f];
    const float2 v1 = hp[(size_t)r1*64 + f];
    const float2 v2 = hp[(size_t)r2*64 + f];
    const float2 v3 = hp[(size_t)r3*64 + f];
    a0 += w0*v0.x + w1*v1.x + w2*v2.x + w3*v3.x;
    a1 += w0*v0.y + w1*v1.y + w2*v2.y + w3*v3.y;
  }
  for (; e < e2; ++e){
    const int r = perm[e]; const float wgt = ew[e];
    const float2 v = hp[(size_t)r*64 + f];
    a0 += wgt*v.x; a1 += wgt*v.y;
  }
  const float2 bb = ((const float2*)bias)[f];
  ((float2*)out)[(size_t)i*64 + f] = make_float2(a0 + bb.x, a1 + bb.y);
}

// ---------------- final dense + softmax ----------------
__global__ __launch_bounds__(256) void dense_kernel(const float* __restrict__ flat,
    const float* __restrict__ linW, float* __restrict__ logits)
{
  const int j   = blockIdx.x;
  const int tid = threadIdx.x;
  const int Q4  = FLATSZ/4;                  // 320000
  const int CH4 = Q4/16;                     // 20000 (gridDim.y == 16)
  const int s4  = blockIdx.y*CH4;
  const int e4  = s4 + CH4;
  const float4* w4 = (const float4*)&linW[(size_t)j*FLATSZ];
  const float4* f4 = (const float4*)flat;
  float part = 0.0f;
  for (int i = s4 + tid; i < e4; i += 256){
    const float4 a = w4[i];
    const float4 b = f4[i];
    part += a.x*b.x + a.y*b.y + a.z*b.z + a.w*b.w;
  }
  __shared__ float red[256];
  red[tid] = part; __syncthreads();
  for (int s = 128; s > 0; s >>= 1){
    if (tid < s) red[tid] += red[tid + s];
    __syncthreads();
  }
  if (tid == 0) atomicAdd(&logits[j], red[0]);
}

__global__ __launch_bounds__(128) void softmax_kernel(const float* __restrict__ logits,
    const float* __restrict__ linb, float* __restrict__ out)
{
  __shared__ float red[128];
  const int tid = threadIdx.x;
  const float v = (tid < OUTD) ? logits[tid] + linb[tid] : -INFINITY;
  red[tid] = v; __syncthreads();
  for (int s = 64; s > 0; s >>= 1){
    if (tid < s) red[tid] = fmaxf(red[tid], red[tid + s]);
    __syncthreads();
  }
  const float mx = red[0]; __syncthreads();
  const float e = (tid < OUTD) ? expf(v - mx) : 0.0f;
  red[tid] = e; __syncthreads();
  for (int s = 64; s > 0; s >>= 1){
    if (tid < s) red[tid] += red[tid + s];
    __syncthreads();
  }
  const float inv = 1.0f/red[0];
  if (tid < OUTD) out[tid] = e*inv;
}

// ---------------- launch ----------------

extern "C" void kernel_launch(void* const* d_in, const int* in_sizes, int n_in,
                              void* d_out, int out_size, void* d_ws, size_t ws_size,
                              hipStream_t stream)
{
  const float* x     = (const float*)d_in[0];
  const int*   ei    = (const int*)  d_in[1];
  const float* W_ih1 = (const float*)d_in[2];
  const float* W_hh1 = (const float*)d_in[3];
  const float* b_ih1 = (const float*)d_in[4];
  const float* b_hh1 = (const float*)d_in[5];
  const float* bias1 = (const float*)d_in[6];
  const float* W_ih2 = (const float*)d_in[7];
  const float* W_hh2 = (const float*)d_in[8];
  const float* b_ih2 = (const float*)d_in[9];
  const float* b_hh2 = (const float*)d_in[10];
  const float* bias2 = (const float*)d_in[11];
  const float* lin_W = (const float*)d_in[12];
  const float* lin_b = (const float*)d_in[13];
  float* out = (float*)d_out;
  const int E = in_sizes[1]/2;
  (void)n_in; (void)out_size; (void)ws_size;

  char* p = (char*)d_ws;
  auto alloc = [&](size_t bytes)->void* {
    void* r = (void*)p;
    p += (bytes + 255) & ~(size_t)255;
    return r;
  };
  int*   cnt    = (int*)  alloc((size_t)NN*4);
  int*   cursor = (int*)  alloc((size_t)NN*4);
  int*   offs   = (int*)  alloc((size_t)(NN+1)*4);
  float* dis    = (float*)alloc((size_t)NN*4);
  int*   perm   = (int*)  alloc((size_t)E*4);
  float* ew     = (float*)alloc((size_t)E*4);
  f16*   h1all  = (f16*)  alloc((size_t)TT*NN*H1C*2);   // 123 MB
  f16*   x2all  = (f16*)  alloc((size_t)TT*NN*H1C*2);   // 123 MB
  float* h2fin  = (float*)alloc((size_t)NN*H2C*4);
  float* out2   = (float*)alloc((size_t)NN*H2C*4);
  f16*   wih1h  = (f16*)  alloc((size_t)3*H1C*DIN*2);
  f16*   whh1h  = (f16*)  alloc((size_t)3*H1C*H1C*2);
  f16*   wih2h  = (f16*)  alloc((size_t)3*H2C*H1C*2);
  f16*   whh2h  = (f16*)  alloc((size_t)3*H2C*H2C*2);
  float* logits = (float*)alloc((size_t)OUTD*4);

  // ---- graph preprocessing ----
  init_kernel   <<<(NN+255)/256, 256, 0, stream>>>(cnt, cursor, logits, NN);
  count_kernel  <<<(E+255)/256, 256, 0, stream>>>(ei, cnt, E);
  dis_kernel    <<<(NN+255)/256, 256, 0, stream>>>(cnt, dis, NN);
  scan_kernel   <<<1, 256, 0, stream>>>(cnt, offs, NN);
  scatter_kernel<<<(E+255)/256, 256, 0, stream>>>(ei, dis, offs, cursor, perm, ew, E);

  // ---- f16 weight casts ----
  cast_f16_kernel<<<((3*H1C*DIN/4)+255)/256, 256, 0, stream>>>((const float4*)W_ih1, (f16x4*)wih1h, 3*H1C*DIN/4);
  cast_f16_kernel<<<((3*H1C*H1C/4)+255)/256, 256, 0, stream>>>((const float4*)W_hh1, (f16x4*)whh1h, 3*H1C*H1C/4);
  cast_f16_kernel<<<((3*H2C*H1C/4)+255)/256, 256, 0, stream>>>((const float4*)W_ih2, (f16x4*)wih2h, 3*H2C*H1C/4);
  cast_f16_kernel<<<((3*H2C*H2C/4)+255)/256, 256, 0, stream>>>((const float4*)W_hh2, (f16x4*)whh2h, 3*H2C*H2C/4);

  const int NB = (NN + 63)/64;   // 157

  // ---- layer-1 GRU chain: one kernel, 24 steps inside ----
  gru1_chain_kernel<<<NB, 512, 2*64*(H1C+8)*2, stream>>>(
      x, wih1h, whh1h, b_ih1, b_hh1, h1all);

  // ---- batched conv1: 48 L2-resident slices, XCD-pinned ----
  conv1_kernel<<<48*NN, 64, 0, stream>>>(h1all, perm, ew, offs, dis, bias1, x2all);

  // ---- layer-2 GRU chain: one kernel ----
  gru2_chain_kernel<<<NB, 512, 2*64*(H2C+8)*2, stream>>>(
      x2all, wih2h, whh2h, b_ih2, b_hh2, h2fin);

  conv2_kernel<<<NN, 64, 0, stream>>>(h2fin, perm, ew, offs, dis, bias2, out2);
  dense_kernel<<<dim3(OUTD, 16), 256, 0, stream>>>(out2, lin_W, logits);
  softmax_kernel<<<1, 128, 0, stream>>>(logits, lin_b, out);
}